// Round 1
// baseline (9992.380 us; speedup 1.0000x reference)
//
#include <hip/hip_runtime.h>

#define D_MODEL 1024
#define N_HEADS 16
#define D_HEAD 64
#define BATCH 4
#define SEQ 2048
#define TOKENS (BATCH * SEQ)   // 8192

typedef __attribute__((ext_vector_type(8))) short short8;
typedef __attribute__((ext_vector_type(4))) float f32x4;

__device__ __forceinline__ unsigned short f2bf(float f) {
    unsigned u = __float_as_uint(f);
    u += 0x7fffu + ((u >> 16) & 1u);   // round-to-nearest-even
    return (unsigned short)(u >> 16);
}
__device__ __forceinline__ float bf2f(unsigned short s) {
    return __uint_as_float(((unsigned)s) << 16);
}

// ---------------- LayerNorm: one block (256 thr) per token, f32 -> bf16 ----------------
__global__ void ln_kernel(const float* __restrict__ X, const float* __restrict__ gamma,
                          const float* __restrict__ beta, unsigned short* __restrict__ Xn) {
    const int t = blockIdx.x;
    const int tid = threadIdx.x;                      // 0..255
    const float4 v = ((const float4*)(X + (size_t)t * D_MODEL))[tid];
    float s  = v.x + v.y + v.z + v.w;
    float s2 = v.x * v.x + v.y * v.y + v.z * v.z + v.w * v.w;
    for (int off = 32; off > 0; off >>= 1) {
        s  += __shfl_xor(s,  off);
        s2 += __shfl_xor(s2, off);
    }
    __shared__ float sh[8];
    const int wv = tid >> 6;
    if ((tid & 63) == 0) { sh[wv] = s; sh[4 + wv] = s2; }
    __syncthreads();
    const float ts  = sh[0] + sh[1] + sh[2] + sh[3];
    const float ts2 = sh[4] + sh[5] + sh[6] + sh[7];
    const float mu  = ts * (1.0f / D_MODEL);
    const float var = ts2 * (1.0f / D_MODEL) - mu * mu;
    const float rs  = rsqrtf(var + 1e-5f);
    const float4 gm = ((const float4*)gamma)[tid];
    const float4 bt = ((const float4*)beta)[tid];
    ushort4 o;
    o.x = f2bf((v.x - mu) * rs * gm.x + bt.x);
    o.y = f2bf((v.y - mu) * rs * gm.y + bt.y);
    o.z = f2bf((v.z - mu) * rs * gm.z + bt.z);
    o.w = f2bf((v.w - mu) * rs * gm.w + bt.w);
    ((ushort4*)Xn)[(size_t)t * (D_MODEL / 4) + tid] = o;
}

// ---------------- f32 -> bf16 weight convert ----------------
__global__ void cvt_kernel(const float* __restrict__ src, unsigned short* __restrict__ dst) {
    const int i = blockIdx.x * blockDim.x + threadIdx.x;   // one float4 per thread
    const float4 v = ((const float4*)src)[i];
    ushort4 o;
    o.x = f2bf(v.x); o.y = f2bf(v.y); o.z = f2bf(v.z); o.w = f2bf(v.w);
    ((ushort4*)dst)[i] = o;
}

// ---------------- NT GEMM: C[M,N] = A[M,K] * B[N,K]^T + bias ----------------
// A, B bf16; one 16x16 output tile per wave; 4 waves/block stacked along M.
// grid = (N/16, M/64), block = 256.
template <bool OUT_BF16>
__global__ void gemm_nt(const unsigned short* __restrict__ A, const unsigned short* __restrict__ B,
                        const float* __restrict__ bias, void* __restrict__ out,
                        int M, int N, int K) {
    const int lane = threadIdx.x & 63;
    const int wave = threadIdx.x >> 6;
    const int m0 = blockIdx.y * 64 + wave * 16;
    const int n0 = blockIdx.x * 16;
    const int r  = lane & 15;            // A row / B row (=output col)
    const int ko = (lane >> 4) * 8;      // k offset within 32
    const short* Ar = (const short*)A + (size_t)(m0 + r) * K + ko;
    const short* Br = (const short*)B + (size_t)(n0 + r) * K + ko;
    f32x4 acc = {0.f, 0.f, 0.f, 0.f};
    for (int k = 0; k < K; k += 32) {
        short8 a = *(const short8*)(Ar + k);
        short8 b = *(const short8*)(Br + k);
        acc = __builtin_amdgcn_mfma_f32_16x16x32_bf16(a, b, acc, 0, 0, 0);
    }
    const int row0 = (lane >> 4) * 4;
    const int cn   = n0 + r;             // output column
    const float bv = bias[cn];
    #pragma unroll
    for (int i = 0; i < 4; ++i) {
        const int m = m0 + row0 + i;
        const float val = acc[i] + bv;
        if (OUT_BF16)
            ((unsigned short*)out)[(size_t)m * N + cn] = f2bf(val);
        else
            ((float*)out)[(size_t)m * N + cn] = val;
    }
}

// ---------------- causal attention, online softmax: one wave per (b,h,q) ----------------
// Q,K,V token-major [TOKENS][D_MODEL] bf16; lane = d within head (D_HEAD==64).
__global__ void attn_kernel(const unsigned short* __restrict__ Q, const unsigned short* __restrict__ K,
                            const unsigned short* __restrict__ V, unsigned short* __restrict__ Mo) {
    const int lane = threadIdx.x & 63;
    const int w = (blockIdx.x << 2) | (threadIdx.x >> 6);  // global wave id
    const int q = w & (SEQ - 1);
    const int h = (w >> 11) & (N_HEADS - 1);
    const int b = w >> 15;
    const size_t base = (size_t)b * SEQ * D_MODEL + (size_t)h * D_HEAD + lane;
    const float qv = bf2f(Q[base + (size_t)q * D_MODEL]) * 0.125f;   // 1/sqrt(64)
    float m = -INFINITY, l = 0.f, acc = 0.f;
    for (int k = 0; k <= q; ++k) {
        float s = qv * bf2f(K[base + (size_t)k * D_MODEL]);
        s += __shfl_xor(s, 32); s += __shfl_xor(s, 16); s += __shfl_xor(s, 8);
        s += __shfl_xor(s, 4);  s += __shfl_xor(s, 2);  s += __shfl_xor(s, 1);
        const float vv = bf2f(V[base + (size_t)k * D_MODEL]);
        const float mn = fmaxf(m, s);
        const float c  = __expf(m - mn);
        const float p  = __expf(s - mn);
        l   = fmaf(l, c, p);
        acc = fmaf(acc, c, p * vv);
        m = mn;
    }
    Mo[base + (size_t)q * D_MODEL] = f2bf(acc / l);
}

extern "C" void kernel_launch(void* const* d_in, const int* in_sizes, int n_in,
                              void* d_out, int out_size, void* d_ws, size_t ws_size,
                              hipStream_t stream) {
    const float* X  = (const float*)d_in[0];
    const float* lg = (const float*)d_in[1];
    const float* lb = (const float*)d_in[2];
    const float* Wq = (const float*)d_in[3];
    const float* bq = (const float*)d_in[4];
    const float* Wk = (const float*)d_in[5];
    const float* bk = (const float*)d_in[6];
    const float* Wv = (const float*)d_in[7];
    const float* bv = (const float*)d_in[8];
    const float* Wo = (const float*)d_in[9];
    const float* bo = (const float*)d_in[10];
    float* out = (float*)d_out;

    char* ws = (char*)d_ws;
    const size_t MB = 1024 * 1024;
    unsigned short* Xn  = (unsigned short*)(ws + 0);          // 16 MB
    unsigned short* WqB = (unsigned short*)(ws + 16 * MB);    // 2 MB each
    unsigned short* WkB = (unsigned short*)(ws + 18 * MB);
    unsigned short* WvB = (unsigned short*)(ws + 20 * MB);
    unsigned short* WoB = (unsigned short*)(ws + 22 * MB);
    unsigned short* Qb  = (unsigned short*)(ws + 24 * MB);    // 16 MB each
    unsigned short* Kb  = (unsigned short*)(ws + 40 * MB);
    unsigned short* Vb  = (unsigned short*)(ws + 56 * MB);
    unsigned short* Mb  = (unsigned short*)(ws + 72 * MB);    // merged AV, 16 MB

    // 1. LayerNorm -> Xn (bf16)
    ln_kernel<<<TOKENS, 256, 0, stream>>>(X, lg, lb, Xn);

    // 2. weights f32 -> bf16 (1M elems each -> 262144 float4s)
    cvt_kernel<<<1024, 256, 0, stream>>>(Wq, WqB);
    cvt_kernel<<<1024, 256, 0, stream>>>(Wk, WkB);
    cvt_kernel<<<1024, 256, 0, stream>>>(Wv, WvB);
    cvt_kernel<<<1024, 256, 0, stream>>>(Wo, WoB);

    // 3. Q/K/V projections: [8192,1024] x [1024,1024]^T
    dim3 ggrid(D_MODEL / 16, TOKENS / 64);
    gemm_nt<true><<<ggrid, 256, 0, stream>>>(Xn, WqB, bq, Qb, TOKENS, D_MODEL, D_MODEL);
    gemm_nt<true><<<ggrid, 256, 0, stream>>>(Xn, WkB, bk, Kb, TOKENS, D_MODEL, D_MODEL);
    gemm_nt<true><<<ggrid, 256, 0, stream>>>(Xn, WvB, bv, Vb, TOKENS, D_MODEL, D_MODEL);

    // 4. causal attention: one wave per (b,h,q) => 131072 waves / 4 per block
    attn_kernel<<<(BATCH * N_HEADS * SEQ) / 4, 256, 0, stream>>>(Qb, Kb, Vb, Mb);

    // 5. output projection -> d_out (f32)
    gemm_nt<false><<<ggrid, 256, 0, stream>>>(Mb, WoB, bo, out, TOKENS, D_MODEL, D_MODEL);
}

// Round 3
// 1309.272 us; speedup vs baseline: 7.6320x; 7.6320x over previous
//
#include <hip/hip_runtime.h>

#define D_MODEL 1024
#define N_HEADS 16
#define D_HEAD 64
#define BATCH 4
#define SEQ 2048
#define TOKENS (BATCH * SEQ)   // 8192

#define QBLK 64
#define KBLK 64
#define KPAD 72   // 64 + 8 bf16 pad -> 144B row stride: 2-way LDS conflict (free per m136)

typedef __attribute__((ext_vector_type(8))) short short8;
typedef __attribute__((ext_vector_type(4))) float f32x4;

__device__ __forceinline__ unsigned short f2bf(float f) {
    unsigned u = __float_as_uint(f);
    u += 0x7fffu + ((u >> 16) & 1u);   // round-to-nearest-even
    return (unsigned short)(u >> 16);
}
__device__ __forceinline__ float bf2f(unsigned short s) {
    return __uint_as_float(((unsigned)s) << 16);
}

// ---------------- LayerNorm: one block (256 thr) per token, f32 -> bf16 ----------------
__global__ void ln_kernel(const float* __restrict__ X, const float* __restrict__ gamma,
                          const float* __restrict__ beta, unsigned short* __restrict__ Xn) {
    const int t = blockIdx.x;
    const int tid = threadIdx.x;                      // 0..255
    const float4 v = ((const float4*)(X + (size_t)t * D_MODEL))[tid];
    float s  = v.x + v.y + v.z + v.w;
    float s2 = v.x * v.x + v.y * v.y + v.z * v.z + v.w * v.w;
    for (int off = 32; off > 0; off >>= 1) {
        s  += __shfl_xor(s,  off);
        s2 += __shfl_xor(s2, off);
    }
    __shared__ float sh[8];
    const int wv = tid >> 6;
    if ((tid & 63) == 0) { sh[wv] = s; sh[4 + wv] = s2; }
    __syncthreads();
    const float ts  = sh[0] + sh[1] + sh[2] + sh[3];
    const float ts2 = sh[4] + sh[5] + sh[6] + sh[7];
    const float mu  = ts * (1.0f / D_MODEL);
    const float var = ts2 * (1.0f / D_MODEL) - mu * mu;
    const float rs  = rsqrtf(var + 1e-5f);
    const float4 gm = ((const float4*)gamma)[tid];
    const float4 bt = ((const float4*)beta)[tid];
    ushort4 o;
    o.x = f2bf((v.x - mu) * rs * gm.x + bt.x);
    o.y = f2bf((v.y - mu) * rs * gm.y + bt.y);
    o.z = f2bf((v.z - mu) * rs * gm.z + bt.z);
    o.w = f2bf((v.w - mu) * rs * gm.w + bt.w);
    ((ushort4*)Xn)[(size_t)t * (D_MODEL / 4) + tid] = o;
}

// ---------------- f32 -> bf16 weight convert ----------------
__global__ void cvt_kernel(const float* __restrict__ src, unsigned short* __restrict__ dst) {
    const int i = blockIdx.x * blockDim.x + threadIdx.x;   // one float4 per thread
    const float4 v = ((const float4*)src)[i];
    ushort4 o;
    o.x = f2bf(v.x); o.y = f2bf(v.y); o.z = f2bf(v.z); o.w = f2bf(v.w);
    ((ushort4*)dst)[i] = o;
}

// ---------------- NT GEMM: C[M,N] = A[M,K] * B[N,K]^T + bias ----------------
// A, B bf16; one 16x16 output tile per wave; 4 waves/block stacked along M.
// grid = (N/16, M/64), block = 256.
template <bool OUT_BF16>
__global__ void gemm_nt(const unsigned short* __restrict__ A, const unsigned short* __restrict__ B,
                        const float* __restrict__ bias, void* __restrict__ out,
                        int M, int N, int K) {
    const int lane = threadIdx.x & 63;
    const int wave = threadIdx.x >> 6;
    const int m0 = blockIdx.y * 64 + wave * 16;
    const int n0 = blockIdx.x * 16;
    const int r  = lane & 15;            // A row / B row (=output col)
    const int ko = (lane >> 4) * 8;      // k offset within 32
    const short* Ar = (const short*)A + (size_t)(m0 + r) * K + ko;
    const short* Br = (const short*)B + (size_t)(n0 + r) * K + ko;
    f32x4 acc = {0.f, 0.f, 0.f, 0.f};
    for (int k = 0; k < K; k += 32) {
        short8 a = *(const short8*)(Ar + k);
        short8 b = *(const short8*)(Br + k);
        acc = __builtin_amdgcn_mfma_f32_16x16x32_bf16(a, b, acc, 0, 0, 0);
    }
    const int row0 = (lane >> 4) * 4;
    const int cn   = n0 + r;             // output column
    const float bv = bias[cn];
    #pragma unroll
    for (int i = 0; i < 4; ++i) {
        const int m = m0 + row0 + i;
        const float val = acc[i] + bv;
        if (OUT_BF16)
            ((unsigned short*)out)[(size_t)m * N + cn] = f2bf(val);
        else
            ((float*)out)[(size_t)m * N + cn] = val;
    }
}

// ---------------- MFMA causal flash attention ----------------
// grid = (32 q-blocks, 64 bh). block = 256 (4 waves). Wave w owns q rows
// q0 + w*16 .. +16. K/V tiles of 64 staged in LDS (V transposed), shared
// by the 4 waves. Online softmax in C/D fragment layout; P re-laid-out
// through a per-wave LDS buffer for the PV A-fragment.
__global__ __launch_bounds__(256) void flash_attn(const unsigned short* __restrict__ Q,
                                                  const unsigned short* __restrict__ K,
                                                  const unsigned short* __restrict__ V,
                                                  unsigned short* __restrict__ Mo) {
    __shared__ unsigned short Kt[KBLK][KPAD];        // [k][d]
    __shared__ unsigned short Vt[D_HEAD][KPAD];      // [d][k] (transposed)
    __shared__ unsigned short Pw[4][16][KPAD];       // per-wave P tile [q][k]

    const int tid  = threadIdx.x;
    const int lane = tid & 63;
    const int w    = tid >> 6;
    const int qb   = blockIdx.x;        // 0..31
    const int bh   = blockIdx.y;        // 0..63
    const int b = bh >> 4, h = bh & 15;
    const int q0 = qb * QBLK;
    const int lg = lane >> 4;           // 0..3
    const int lr = lane & 15;           // 0..15

    const size_t tokbase = (size_t)b * SEQ;
    const size_t hoff = (size_t)h * D_HEAD;

    // Q fragments hoisted: rows q0 + w*16 + lr, d-cols lg*8 (+32)
    const short* Qp = (const short*)Q + (tokbase + q0 + w * 16 + lr) * D_MODEL + hoff + lg * 8;
    const short8 qf0 = *(const short8*)(Qp);
    const short8 qf1 = *(const short8*)(Qp + 32);

    float m[4], l[4];
    f32x4 acc[4];                       // acc[ds]: output d-subtile ds, rows lg*4+i
    #pragma unroll
    for (int i = 0; i < 4; ++i) { m[i] = -INFINITY; l[i] = 0.f; acc[i] = (f32x4){0.f,0.f,0.f,0.f}; }

    const int ntiles = qb + 1;          // causal: k0 <= q0+63
    for (int t = 0; t < ntiles; ++t) {
        const int k0 = t * KBLK;
        __syncthreads();                // previous tile's LDS reads done
        {   // stage K row-major and V transposed: thread -> row tid>>2, 16 cols
            const int r = tid >> 2, c = (tid & 3) * 16;
            const short* ks = (const short*)K + (tokbase + k0 + r) * D_MODEL + hoff + c;
            *(short8*)&Kt[r][c]     = *(const short8*)ks;
            *(short8*)&Kt[r][c + 8] = *(const short8*)(ks + 8);
            const short* vs = (const short*)V + (tokbase + k0 + r) * D_MODEL + hoff + c;
            const short8 v0 = *(const short8*)vs;
            const short8 v1 = *(const short8*)(vs + 8);
            #pragma unroll
            for (int j = 0; j < 8; ++j) {
                Vt[c + j][r]     = (unsigned short)v0[j];
                Vt[c + 8 + j][r] = (unsigned short)v1[j];
            }
        }
        __syncthreads();

        // QK^T: 4 k-subtiles of 16 cols, K-dim 64 = 2 MFMA each
        f32x4 sc[4];
        #pragma unroll
        for (int s4 = 0; s4 < 4; ++s4) {
            const short8 kf0 = *(const short8*)&Kt[s4 * 16 + lr][lg * 8];
            const short8 kf1 = *(const short8*)&Kt[s4 * 16 + lr][lg * 8 + 32];
            f32x4 z = {0.f, 0.f, 0.f, 0.f};
            z = __builtin_amdgcn_mfma_f32_16x16x32_bf16(qf0, kf0, z, 0, 0, 0);
            z = __builtin_amdgcn_mfma_f32_16x16x32_bf16(qf1, kf1, z, 0, 0, 0);
            sc[s4] = z;
        }

        // scale + causal mask (C/D layout: col = lr, row = lg*4+i)
        const int gqr = q0 + w * 16 + lg * 4;
        #pragma unroll
        for (int s4 = 0; s4 < 4; ++s4) {
            const int gk = k0 + s4 * 16 + lr;
            #pragma unroll
            for (int i = 0; i < 4; ++i) {
                const float s = sc[s4][i] * 0.125f;
                sc[s4][i] = (gk <= gqr + i) ? s : -INFINITY;
            }
        }

        // online softmax: row reduce across the 16-lane group
        float c_[4];
        #pragma unroll
        for (int i = 0; i < 4; ++i) {
            float rm = fmaxf(fmaxf(sc[0][i], sc[1][i]), fmaxf(sc[2][i], sc[3][i]));
            rm = fmaxf(rm, __shfl_xor(rm, 1));
            rm = fmaxf(rm, __shfl_xor(rm, 2));
            rm = fmaxf(rm, __shfl_xor(rm, 4));
            rm = fmaxf(rm, __shfl_xor(rm, 8));
            const float mn = fmaxf(m[i], rm);
            c_[i] = __expf(m[i] - mn);
            m[i] = mn;
        }
        #pragma unroll
        for (int i = 0; i < 4; ++i) {
            float rs = 0.f;
            #pragma unroll
            for (int s4 = 0; s4 < 4; ++s4) {
                const float p = __expf(sc[s4][i] - m[i]);
                sc[s4][i] = p;
                rs += p;
            }
            rs += __shfl_xor(rs, 1); rs += __shfl_xor(rs, 2);
            rs += __shfl_xor(rs, 4); rs += __shfl_xor(rs, 8);
            l[i] = l[i] * c_[i] + rs;
            #pragma unroll
            for (int ds = 0; ds < 4; ++ds) acc[ds][i] *= c_[i];
        }

        // P -> LDS (re-layout for A fragment), then PV
        #pragma unroll
        for (int s4 = 0; s4 < 4; ++s4)
            #pragma unroll
            for (int i = 0; i < 4; ++i)
                Pw[w][lg * 4 + i][s4 * 16 + lr] = f2bf(sc[s4][i]);

        #pragma unroll
        for (int c2 = 0; c2 < 2; ++c2) {
            const short8 pf = *(const short8*)&Pw[w][lr][lg * 8 + 32 * c2];
            #pragma unroll
            for (int ds = 0; ds < 4; ++ds) {
                const short8 vf = *(const short8*)&Vt[ds * 16 + lr][lg * 8 + 32 * c2];
                acc[ds] = __builtin_amdgcn_mfma_f32_16x16x32_bf16(pf, vf, acc[ds], 0, 0, 0);
            }
        }
    }

    // epilogue: divide by l, write merged [token][h*64+d]
    const int gq = q0 + w * 16 + lg * 4;
    #pragma unroll
    for (int ds = 0; ds < 4; ++ds) {
        #pragma unroll
        for (int i = 0; i < 4; ++i) {
            const float o = acc[ds][i] / l[i];
            Mo[(tokbase + gq + i) * D_MODEL + hoff + ds * 16 + lr] = f2bf(o);
        }
    }
}

extern "C" void kernel_launch(void* const* d_in, const int* in_sizes, int n_in,
                              void* d_out, int out_size, void* d_ws, size_t ws_size,
                              hipStream_t stream) {
    const float* X  = (const float*)d_in[0];
    const float* lg = (const float*)d_in[1];
    const float* lb = (const float*)d_in[2];
    const float* Wq = (const float*)d_in[3];
    const float* bq = (const float*)d_in[4];
    const float* Wk = (const float*)d_in[5];
    const float* bk = (const float*)d_in[6];
    const float* Wv = (const float*)d_in[7];
    const float* bv = (const float*)d_in[8];
    const float* Wo = (const float*)d_in[9];
    const float* bo = (const float*)d_in[10];
    float* out = (float*)d_out;

    char* ws = (char*)d_ws;
    const size_t MB = 1024 * 1024;
    unsigned short* Xn  = (unsigned short*)(ws + 0);          // 16 MB
    unsigned short* WqB = (unsigned short*)(ws + 16 * MB);    // 2 MB each
    unsigned short* WkB = (unsigned short*)(ws + 18 * MB);
    unsigned short* WvB = (unsigned short*)(ws + 20 * MB);
    unsigned short* WoB = (unsigned short*)(ws + 22 * MB);
    unsigned short* Qb  = (unsigned short*)(ws + 24 * MB);    // 16 MB each
    unsigned short* Kb  = (unsigned short*)(ws + 40 * MB);
    unsigned short* Vb  = (unsigned short*)(ws + 56 * MB);
    unsigned short* Mb  = (unsigned short*)(ws + 72 * MB);    // merged AV, 16 MB

    // 1. LayerNorm -> Xn (bf16)
    ln_kernel<<<TOKENS, 256, 0, stream>>>(X, lg, lb, Xn);

    // 2. weights f32 -> bf16
    cvt_kernel<<<1024, 256, 0, stream>>>(Wq, WqB);
    cvt_kernel<<<1024, 256, 0, stream>>>(Wk, WkB);
    cvt_kernel<<<1024, 256, 0, stream>>>(Wv, WvB);
    cvt_kernel<<<1024, 256, 0, stream>>>(Wo, WoB);

    // 3. Q/K/V projections
    dim3 ggrid(D_MODEL / 16, TOKENS / 64);
    gemm_nt<true><<<ggrid, 256, 0, stream>>>(Xn, WqB, bq, Qb, TOKENS, D_MODEL, D_MODEL);
    gemm_nt<true><<<ggrid, 256, 0, stream>>>(Xn, WkB, bk, Kb, TOKENS, D_MODEL, D_MODEL);
    gemm_nt<true><<<ggrid, 256, 0, stream>>>(Xn, WvB, bv, Vb, TOKENS, D_MODEL, D_MODEL);

    // 4. MFMA causal flash attention
    dim3 agrid(SEQ / QBLK, BATCH * N_HEADS);
    flash_attn<<<agrid, 256, 0, stream>>>(Qb, Kb, Vb, Mb);

    // 5. output projection -> d_out (f32)
    gemm_nt<false><<<ggrid, 256, 0, stream>>>(Mb, WoB, bo, out, TOKENS, D_MODEL, D_MODEL);
}

// Round 4
// 441.959 us; speedup vs baseline: 22.6093x; 2.9624x over previous
//
#include <hip/hip_runtime.h>

#define D_MODEL 1024
#define N_HEADS 16
#define D_HEAD 64
#define BATCH 4
#define SEQ 2048
#define TOKENS (BATCH * SEQ)   // 8192

#define QBLK 64
#define KBLK 64

typedef __attribute__((ext_vector_type(8))) short short8;
typedef __attribute__((ext_vector_type(4))) float f32x4;

__device__ __forceinline__ unsigned short f2bf(float f) {
    unsigned u = __float_as_uint(f);
    u += 0x7fffu + ((u >> 16) & 1u);   // round-to-nearest-even
    return (unsigned short)(u >> 16);
}
__device__ __forceinline__ float bf2f(unsigned short s) {
    return __uint_as_float(((unsigned)s) << 16);
}
__device__ __forceinline__ void gload16(const unsigned short* g, unsigned short* lds) {
    __builtin_amdgcn_global_load_lds((const __attribute__((address_space(1))) void*)g,
                                     (__attribute__((address_space(3))) void*)lds, 16, 0, 0);
}

// ---------------- LayerNorm: one block (256 thr) per token, f32 -> bf16 ----------------
__global__ void ln_kernel(const float* __restrict__ X, const float* __restrict__ gamma,
                          const float* __restrict__ beta, unsigned short* __restrict__ Xn) {
    const int t = blockIdx.x;
    const int tid = threadIdx.x;                      // 0..255
    const float4 v = ((const float4*)(X + (size_t)t * D_MODEL))[tid];
    float s  = v.x + v.y + v.z + v.w;
    float s2 = v.x * v.x + v.y * v.y + v.z * v.z + v.w * v.w;
    for (int off = 32; off > 0; off >>= 1) {
        s  += __shfl_xor(s,  off);
        s2 += __shfl_xor(s2, off);
    }
    __shared__ float sh[8];
    const int wv = tid >> 6;
    if ((tid & 63) == 0) { sh[wv] = s; sh[4 + wv] = s2; }
    __syncthreads();
    const float ts  = sh[0] + sh[1] + sh[2] + sh[3];
    const float ts2 = sh[4] + sh[5] + sh[6] + sh[7];
    const float mu  = ts * (1.0f / D_MODEL);
    const float var = ts2 * (1.0f / D_MODEL) - mu * mu;
    const float rs  = rsqrtf(var + 1e-5f);
    const float4 gm = ((const float4*)gamma)[tid];
    const float4 bt = ((const float4*)beta)[tid];
    ushort4 o;
    o.x = f2bf((v.x - mu) * rs * gm.x + bt.x);
    o.y = f2bf((v.y - mu) * rs * gm.y + bt.y);
    o.z = f2bf((v.z - mu) * rs * gm.z + bt.z);
    o.w = f2bf((v.w - mu) * rs * gm.w + bt.w);
    ((ushort4*)Xn)[(size_t)t * (D_MODEL / 4) + tid] = o;
}

// ---------------- f32 -> bf16 weight convert ----------------
__global__ void cvt_kernel(const float* __restrict__ src, unsigned short* __restrict__ dst) {
    const int i = blockIdx.x * blockDim.x + threadIdx.x;   // one float4 per thread
    const float4 v = ((const float4*)src)[i];
    ushort4 o;
    o.x = f2bf(v.x); o.y = f2bf(v.y); o.z = f2bf(v.z); o.w = f2bf(v.w);
    ((ushort4*)dst)[i] = o;
}

// ---------------- coalesced 2048x1024 per-batch transpose (V -> V^T) ----------------
// out[(b*D_MODEL + n)*SEQ + s] = in[(b*SEQ + s)*D_MODEL + n]
__global__ void transpose_v(const unsigned short* __restrict__ in, unsigned short* __restrict__ out) {
    __shared__ __attribute__((aligned(16))) unsigned short T[64][72];
    const int tid = threadIdx.x;
    const int s0 = blockIdx.x * 64;
    const int n0 = blockIdx.y * 64;
    const int b  = blockIdx.z;
    const int r = tid >> 2, c = (tid & 3) * 16;
    const unsigned short* ip = in + ((size_t)(b * SEQ + s0 + r)) * D_MODEL + n0 + c;
    *(short8*)&T[r][c]     = *(const short8*)ip;
    *(short8*)&T[r][c + 8] = *(const short8*)(ip + 8);
    __syncthreads();
    unsigned short* op = out + ((size_t)(b * D_MODEL + n0 + r)) * SEQ + s0 + c;
    short8 o0, o1;
    #pragma unroll
    for (int j = 0; j < 8; ++j) { o0[j] = (short)T[c + j][r]; o1[j] = (short)T[c + 8 + j][r]; }
    *(short8*)op       = o0;
    *(short8*)(op + 8) = o1;
}

// ---------------- 128x128-tile NT GEMM (m97 structure) ----------------
// C[M,N] = A[M,K] * B[N,K]^T + bias. BK=64. 4 waves (2x2), 64x64 out each.
// LDS linear + XOR slot-swizzle (slot ^= row&7); global source pre-swizzled
// so global_load_lds's linear dest lands data at swizzled locations.
template <bool OUT_BF16>
__global__ __launch_bounds__(256) void gemm128(const unsigned short* __restrict__ A,
                                               const unsigned short* __restrict__ B,
                                               const float* __restrict__ bias, void* __restrict__ out,
                                               int M, int N, int K) {
    __shared__ __attribute__((aligned(16))) unsigned short As[128 * 64];   // 16 KB
    __shared__ __attribute__((aligned(16))) unsigned short Bs[128 * 64];   // 16 KB
    const int tid  = threadIdx.x;
    const int lane = tid & 63;
    const int w    = tid >> 6;
    const int wm = w >> 1, wn = w & 1;
    const int m0 = blockIdx.y * 128;
    const int n0 = blockIdx.x * 128;
    const int lr = lane & 15, lg = lane >> 4;

    // staging geometry: chunk = 1KB = 8 rows of 128B; lane -> (row in chunk, slot)
    const int crow  = lane >> 3;          // 0..7
    const int uslot = (lane & 7) ^ crow;  // inverse-swizzled source slot

    f32x4 acc[4][4] = {};
    for (int k0 = 0; k0 < K; k0 += 64) {
        __syncthreads();
        #pragma unroll
        for (int i = 0; i < 4; ++i) {
            const int c = w * 4 + i;               // 16 chunks per matrix
            const int grow = c * 8 + crow;
            gload16(A + (size_t)(m0 + grow) * K + k0 + uslot * 8, As + c * 512);
            gload16(B + (size_t)(n0 + grow) * K + k0 + uslot * 8, Bs + c * 512);
        }
        __syncthreads();
        #pragma unroll
        for (int h = 0; h < 2; ++h) {              // two 32-k halves
            short8 af[4], bf[4];
            #pragma unroll
            for (int mi = 0; mi < 4; ++mi) {
                const int row = wm * 64 + mi * 16 + lr;
                const int slot = (h * 4 + lg) ^ (row & 7);
                af[mi] = *(const short8*)(As + row * 64 + slot * 8);
            }
            #pragma unroll
            for (int ni = 0; ni < 4; ++ni) {
                const int row = wn * 64 + ni * 16 + lr;
                const int slot = (h * 4 + lg) ^ (row & 7);
                bf[ni] = *(const short8*)(Bs + row * 64 + slot * 8);
            }
            #pragma unroll
            for (int mi = 0; mi < 4; ++mi)
                #pragma unroll
                for (int ni = 0; ni < 4; ++ni)
                    acc[mi][ni] = __builtin_amdgcn_mfma_f32_16x16x32_bf16(af[mi], bf[ni], acc[mi][ni], 0, 0, 0);
        }
    }
    #pragma unroll
    for (int ni = 0; ni < 4; ++ni) {
        const int n = n0 + wn * 64 + ni * 16 + lr;
        const float bv = bias[n];
        #pragma unroll
        for (int mi = 0; mi < 4; ++mi) {
            const int mb = m0 + wm * 64 + mi * 16 + lg * 4;
            #pragma unroll
            for (int i = 0; i < 4; ++i) {
                const float val = acc[mi][ni][i] + bv;
                if (OUT_BF16) ((unsigned short*)out)[(size_t)(mb + i) * N + n] = f2bf(val);
                else          ((float*)out)[(size_t)(mb + i) * N + n] = val;
            }
        }
    }
}

// ---------------- MFMA causal flash attention ----------------
// grid = (32 q-blocks, 64 bh). 4 waves; wave w owns q rows q0+w*16..+16.
// K [k][d] and V^T [d][s] tiles staged via global_load_lds into swizzled
// linear LDS (slot ^= row&7); fragments read as conflict-free ds_read_b128.
__global__ __launch_bounds__(256) void flash_attn(const unsigned short* __restrict__ Q,
                                                  const unsigned short* __restrict__ K,
                                                  const unsigned short* __restrict__ Vt,
                                                  unsigned short* __restrict__ Mo) {
    __shared__ __attribute__((aligned(16))) unsigned short Kt[KBLK * 64];  // 8 KB
    __shared__ __attribute__((aligned(16))) unsigned short Vs[64 * KBLK];  // 8 KB
    __shared__ __attribute__((aligned(16))) unsigned short Pw[4][16][72];  // 9 KB

    const int tid  = threadIdx.x;
    const int lane = tid & 63;
    const int w    = tid >> 6;
    const int qb   = blockIdx.x;
    const int bh   = blockIdx.y;        // b*16 + h
    const int b = bh >> 4, h = bh & 15;
    const int q0 = qb * QBLK;
    const int lg = lane >> 4;
    const int lr = lane & 15;

    const size_t tokbase = (size_t)b * SEQ;
    const size_t hoff = (size_t)h * D_HEAD;

    const int crow  = lane >> 3;
    const int uslot = (lane & 7) ^ crow;

    const short* Qp = (const short*)Q + (tokbase + q0 + w * 16 + lr) * D_MODEL + hoff + lg * 8;
    const short8 qf0 = *(const short8*)(Qp);
    const short8 qf1 = *(const short8*)(Qp + 32);

    float m[4], l[4];
    f32x4 acc[4];
    #pragma unroll
    for (int i = 0; i < 4; ++i) { m[i] = -INFINITY; l[i] = 0.f; acc[i] = (f32x4){0.f,0.f,0.f,0.f}; }

    const int ntiles = qb + 1;
    for (int t = 0; t < ntiles; ++t) {
        const int k0 = t * KBLK;
        __syncthreads();
        #pragma unroll
        for (int i = 0; i < 2; ++i) {
            const int c = w * 2 + i;            // 8 chunks each
            const int row = c * 8 + crow;
            // K tile: rows = k-token, cols = d
            gload16(K + (tokbase + k0 + row) * D_MODEL + hoff + uslot * 8, Kt + c * 512);
            // V^T tile: rows = d, cols = s-token
            gload16(Vt + ((size_t)bh * 64 + row) * SEQ + k0 + uslot * 8, Vs + c * 512);
        }
        __syncthreads();

        // QK^T
        f32x4 sc[4];
        #pragma unroll
        for (int s4 = 0; s4 < 4; ++s4) {
            const int row = s4 * 16 + lr;
            const short8 kf0 = *(const short8*)(Kt + row * 64 + ((lg)     ^ (row & 7)) * 8);
            const short8 kf1 = *(const short8*)(Kt + row * 64 + ((4 + lg) ^ (row & 7)) * 8);
            f32x4 z = {0.f, 0.f, 0.f, 0.f};
            z = __builtin_amdgcn_mfma_f32_16x16x32_bf16(qf0, kf0, z, 0, 0, 0);
            z = __builtin_amdgcn_mfma_f32_16x16x32_bf16(qf1, kf1, z, 0, 0, 0);
            sc[s4] = z;
        }

        // scale + causal mask (C/D: col = lr -> k, row = lg*4+i -> q)
        const int gqr = q0 + w * 16 + lg * 4;
        #pragma unroll
        for (int s4 = 0; s4 < 4; ++s4) {
            const int gk = k0 + s4 * 16 + lr;
            #pragma unroll
            for (int i = 0; i < 4; ++i) {
                const float s = sc[s4][i] * 0.125f;
                sc[s4][i] = (gk <= gqr + i) ? s : -INFINITY;
            }
        }

        // online softmax
        float c_[4];
        #pragma unroll
        for (int i = 0; i < 4; ++i) {
            float rm = fmaxf(fmaxf(sc[0][i], sc[1][i]), fmaxf(sc[2][i], sc[3][i]));
            rm = fmaxf(rm, __shfl_xor(rm, 1));
            rm = fmaxf(rm, __shfl_xor(rm, 2));
            rm = fmaxf(rm, __shfl_xor(rm, 4));
            rm = fmaxf(rm, __shfl_xor(rm, 8));
            const float mn = fmaxf(m[i], rm);
            c_[i] = __expf(m[i] - mn);
            m[i] = mn;
        }
        #pragma unroll
        for (int i = 0; i < 4; ++i) {
            float rs = 0.f;
            #pragma unroll
            for (int s4 = 0; s4 < 4; ++s4) {
                const float p = __expf(sc[s4][i] - m[i]);
                sc[s4][i] = p;
                rs += p;
            }
            rs += __shfl_xor(rs, 1); rs += __shfl_xor(rs, 2);
            rs += __shfl_xor(rs, 4); rs += __shfl_xor(rs, 8);
            l[i] = l[i] * c_[i] + rs;
            #pragma unroll
            for (int ds = 0; ds < 4; ++ds) acc[ds][i] *= c_[i];
        }

        // P -> per-wave LDS, then PV
        #pragma unroll
        for (int s4 = 0; s4 < 4; ++s4)
            #pragma unroll
            for (int i = 0; i < 4; ++i)
                Pw[w][lg * 4 + i][s4 * 16 + lr] = f2bf(sc[s4][i]);

        #pragma unroll
        for (int c2 = 0; c2 < 2; ++c2) {
            const short8 pf = *(const short8*)&Pw[w][lr][lg * 8 + 32 * c2];
            #pragma unroll
            for (int ds = 0; ds < 4; ++ds) {
                const int row = ds * 16 + lr;
                const short8 vf = *(const short8*)(Vs + row * 64 + ((c2 * 4 + lg) ^ (row & 7)) * 8);
                acc[ds] = __builtin_amdgcn_mfma_f32_16x16x32_bf16(pf, vf, acc[ds], 0, 0, 0);
            }
        }
    }

    const int gq = q0 + w * 16 + lg * 4;
    #pragma unroll
    for (int ds = 0; ds < 4; ++ds) {
        #pragma unroll
        for (int i = 0; i < 4; ++i) {
            const float o = acc[ds][i] / l[i];
            Mo[(tokbase + gq + i) * D_MODEL + hoff + ds * 16 + lr] = f2bf(o);
        }
    }
}

extern "C" void kernel_launch(void* const* d_in, const int* in_sizes, int n_in,
                              void* d_out, int out_size, void* d_ws, size_t ws_size,
                              hipStream_t stream) {
    const float* X  = (const float*)d_in[0];
    const float* lg = (const float*)d_in[1];
    const float* lb = (const float*)d_in[2];
    const float* Wq = (const float*)d_in[3];
    const float* bq = (const float*)d_in[4];
    const float* Wk = (const float*)d_in[5];
    const float* bk = (const float*)d_in[6];
    const float* Wv = (const float*)d_in[7];
    const float* bv = (const float*)d_in[8];
    const float* Wo = (const float*)d_in[9];
    const float* bo = (const float*)d_in[10];
    float* out = (float*)d_out;

    char* ws = (char*)d_ws;
    const size_t MB = 1024 * 1024;
    unsigned short* Xn  = (unsigned short*)(ws + 0);          // 16 MB
    unsigned short* WqB = (unsigned short*)(ws + 16 * MB);    // 2 MB each
    unsigned short* WkB = (unsigned short*)(ws + 18 * MB);
    unsigned short* WvB = (unsigned short*)(ws + 20 * MB);
    unsigned short* WoB = (unsigned short*)(ws + 22 * MB);
    unsigned short* Qb  = (unsigned short*)(ws + 24 * MB);    // 16 MB each
    unsigned short* Kb  = (unsigned short*)(ws + 40 * MB);
    unsigned short* Vb  = (unsigned short*)(ws + 56 * MB);    // raw V (dead after transpose)
    unsigned short* Vtg = (unsigned short*)(ws + 72 * MB);    // V^T [b*D+n][s]
    unsigned short* Mb  = (unsigned short*)(ws + 56 * MB);    // merged AV, overwrites Vb

    // 1. LayerNorm -> Xn (bf16)
    ln_kernel<<<TOKENS, 256, 0, stream>>>(X, lg, lb, Xn);

    // 2. weights f32 -> bf16
    cvt_kernel<<<1024, 256, 0, stream>>>(Wq, WqB);
    cvt_kernel<<<1024, 256, 0, stream>>>(Wk, WkB);
    cvt_kernel<<<1024, 256, 0, stream>>>(Wv, WvB);
    cvt_kernel<<<1024, 256, 0, stream>>>(Wo, WoB);

    // 3. Q/K/V projections: 128x128 tiles
    dim3 ggrid(D_MODEL / 128, TOKENS / 128);
    gemm128<true><<<ggrid, 256, 0, stream>>>(Xn, WqB, bq, Qb, TOKENS, D_MODEL, D_MODEL);
    gemm128<true><<<ggrid, 256, 0, stream>>>(Xn, WkB, bk, Kb, TOKENS, D_MODEL, D_MODEL);
    gemm128<true><<<ggrid, 256, 0, stream>>>(Xn, WvB, bv, Vb, TOKENS, D_MODEL, D_MODEL);

    // 3b. V -> V^T
    dim3 tgrid(SEQ / 64, D_MODEL / 64, BATCH);
    transpose_v<<<tgrid, 256, 0, stream>>>(Vb, Vtg);

    // 4. MFMA causal flash attention
    dim3 agrid(SEQ / QBLK, BATCH * N_HEADS);
    flash_attn<<<agrid, 256, 0, stream>>>(Qb, Kb, Vtg, Mb);

    // 5. output projection -> d_out (f32)
    gemm128<false><<<ggrid, 256, 0, stream>>>(Mb, WoB, bo, out, TOKENS, D_MODEL, D_MODEL);
}

// Round 5
// 373.629 us; speedup vs baseline: 26.7442x; 1.1829x over previous
//
#include <hip/hip_runtime.h>

#define D_MODEL 1024
#define N_HEADS 16
#define D_HEAD 64
#define BATCH 4
#define SEQ 2048
#define TOKENS (BATCH * SEQ)   // 8192

#define QBLK 64
#define KBLK 64

typedef __attribute__((ext_vector_type(8))) short short8;
typedef __attribute__((ext_vector_type(4))) float f32x4;

__device__ __forceinline__ unsigned short f2bf(float f) {
    unsigned u = __float_as_uint(f);
    u += 0x7fffu + ((u >> 16) & 1u);   // round-to-nearest-even
    return (unsigned short)(u >> 16);
}
__device__ __forceinline__ float bf2f(unsigned short s) {
    return __uint_as_float(((unsigned)s) << 16);
}
__device__ __forceinline__ void gload16(const unsigned short* g, unsigned short* lds) {
    __builtin_amdgcn_global_load_lds((const __attribute__((address_space(1))) void*)g,
                                     (__attribute__((address_space(3))) void*)lds, 16, 0, 0);
}

// ---------------- LayerNorm: one block (256 thr) per token, f32 -> bf16 ----------------
__global__ void ln_kernel(const float* __restrict__ X, const float* __restrict__ gamma,
                          const float* __restrict__ beta, unsigned short* __restrict__ Xn) {
    const int t = blockIdx.x;
    const int tid = threadIdx.x;                      // 0..255
    const float4 v = ((const float4*)(X + (size_t)t * D_MODEL))[tid];
    float s  = v.x + v.y + v.z + v.w;
    float s2 = v.x * v.x + v.y * v.y + v.z * v.z + v.w * v.w;
    for (int off = 32; off > 0; off >>= 1) {
        s  += __shfl_xor(s,  off);
        s2 += __shfl_xor(s2, off);
    }
    __shared__ float sh[8];
    const int wv = tid >> 6;
    if ((tid & 63) == 0) { sh[wv] = s; sh[4 + wv] = s2; }
    __syncthreads();
    const float ts  = sh[0] + sh[1] + sh[2] + sh[3];
    const float ts2 = sh[4] + sh[5] + sh[6] + sh[7];
    const float mu  = ts * (1.0f / D_MODEL);
    const float var = ts2 * (1.0f / D_MODEL) - mu * mu;
    const float rs  = rsqrtf(var + 1e-5f);
    const float4 gm = ((const float4*)gamma)[tid];
    const float4 bt = ((const float4*)beta)[tid];
    ushort4 o;
    o.x = f2bf((v.x - mu) * rs * gm.x + bt.x);
    o.y = f2bf((v.y - mu) * rs * gm.y + bt.y);
    o.z = f2bf((v.z - mu) * rs * gm.z + bt.z);
    o.w = f2bf((v.w - mu) * rs * gm.w + bt.w);
    ((ushort4*)Xn)[(size_t)t * (D_MODEL / 4) + tid] = o;
}

// ---------------- f32 -> bf16 weight convert ----------------
__global__ void cvt_kernel(const float* __restrict__ src, unsigned short* __restrict__ dst) {
    const int i = blockIdx.x * blockDim.x + threadIdx.x;   // one float4 per thread
    const float4 v = ((const float4*)src)[i];
    ushort4 o;
    o.x = f2bf(v.x); o.y = f2bf(v.y); o.z = f2bf(v.z); o.w = f2bf(v.w);
    ((ushort4*)dst)[i] = o;
}

// ---------------- coalesced 2048x1024 per-batch transpose (V -> V^T) ----------------
__global__ void transpose_v(const unsigned short* __restrict__ in, unsigned short* __restrict__ out) {
    __shared__ __attribute__((aligned(16))) unsigned short T[64][72];
    const int tid = threadIdx.x;
    const int s0 = blockIdx.x * 64;
    const int n0 = blockIdx.y * 64;
    const int b  = blockIdx.z;
    const int r = tid >> 2, c = (tid & 3) * 16;
    const unsigned short* ip = in + ((size_t)(b * SEQ + s0 + r)) * D_MODEL + n0 + c;
    *(short8*)&T[r][c]     = *(const short8*)ip;
    *(short8*)&T[r][c + 8] = *(const short8*)(ip + 8);
    __syncthreads();
    unsigned short* op = out + ((size_t)(b * D_MODEL + n0 + r)) * SEQ + s0 + c;
    short8 o0, o1;
    #pragma unroll
    for (int j = 0; j < 8; ++j) { o0[j] = (short)T[c + j][r]; o1[j] = (short)T[c + 8 + j][r]; }
    *(short8*)op       = o0;
    *(short8*)(op + 8) = o1;
}

// ---------------- 128x128-tile NT GEMM (m97 structure) ----------------
// C = (A * B^T + bias) * oscale. BK=64. 4 waves (2x2), 64x64 out each.
template <bool OUT_BF16>
__global__ __launch_bounds__(256) void gemm128(const unsigned short* __restrict__ A,
                                               const unsigned short* __restrict__ B,
                                               const float* __restrict__ bias, void* __restrict__ out,
                                               int M, int N, int K, float oscale) {
    __shared__ __attribute__((aligned(16))) unsigned short As[128 * 64];   // 16 KB
    __shared__ __attribute__((aligned(16))) unsigned short Bs[128 * 64];   // 16 KB
    const int tid  = threadIdx.x;
    const int lane = tid & 63;
    const int w    = tid >> 6;
    const int wm = w >> 1, wn = w & 1;
    const int m0 = blockIdx.y * 128;
    const int n0 = blockIdx.x * 128;
    const int lr = lane & 15, lg = lane >> 4;

    const int crow  = lane >> 3;          // 0..7
    const int uslot = (lane & 7) ^ crow;  // inverse-swizzled source slot

    f32x4 acc[4][4] = {};
    for (int k0 = 0; k0 < K; k0 += 64) {
        __syncthreads();
        #pragma unroll
        for (int i = 0; i < 4; ++i) {
            const int c = w * 4 + i;
            const int grow = c * 8 + crow;
            gload16(A + (size_t)(m0 + grow) * K + k0 + uslot * 8, As + c * 512);
            gload16(B + (size_t)(n0 + grow) * K + k0 + uslot * 8, Bs + c * 512);
        }
        __syncthreads();
        #pragma unroll
        for (int h = 0; h < 2; ++h) {
            short8 af[4], bf[4];
            #pragma unroll
            for (int mi = 0; mi < 4; ++mi) {
                const int row = wm * 64 + mi * 16 + lr;
                const int slot = (h * 4 + lg) ^ (row & 7);
                af[mi] = *(const short8*)(As + row * 64 + slot * 8);
            }
            #pragma unroll
            for (int ni = 0; ni < 4; ++ni) {
                const int row = wn * 64 + ni * 16 + lr;
                const int slot = (h * 4 + lg) ^ (row & 7);
                bf[ni] = *(const short8*)(Bs + row * 64 + slot * 8);
            }
            #pragma unroll
            for (int mi = 0; mi < 4; ++mi)
                #pragma unroll
                for (int ni = 0; ni < 4; ++ni)
                    acc[mi][ni] = __builtin_amdgcn_mfma_f32_16x16x32_bf16(af[mi], bf[ni], acc[mi][ni], 0, 0, 0);
        }
    }
    #pragma unroll
    for (int ni = 0; ni < 4; ++ni) {
        const int n = n0 + wn * 64 + ni * 16 + lr;
        const float bv = bias[n];
        #pragma unroll
        for (int mi = 0; mi < 4; ++mi) {
            const int mb = m0 + wm * 64 + mi * 16 + lg * 4;
            #pragma unroll
            for (int i = 0; i < 4; ++i) {
                const float val = (acc[mi][ni][i] + bv) * oscale;
                if (OUT_BF16) ((unsigned short*)out)[(size_t)(mb + i) * N + n] = f2bf(val);
                else          ((float*)out)[(size_t)(mb + i) * N + n] = val;
            }
        }
    }
}

// ---------------- MFMA causal flash attention, 2-phase pipelined ----------------
// 1D grid of 2048 blocks, XCD-grouped (blocks of one bh land on one XCD) and
// heavy q-blocks first. 4 waves; wave w owns q rows q0+w*16..+16.
// K/V^T double-buffered in swizzled LDS via global_load_lds; one barrier/tile.
// Q pre-scaled by 0.125*log2(e) => softmax in exp2 domain.
__global__ __launch_bounds__(256) void flash_attn(const unsigned short* __restrict__ Q,
                                                  const unsigned short* __restrict__ K,
                                                  const unsigned short* __restrict__ Vt,
                                                  unsigned short* __restrict__ Mo) {
    __shared__ __attribute__((aligned(16))) unsigned short KtL[2][KBLK * 64];  // 2x8 KB
    __shared__ __attribute__((aligned(16))) unsigned short VsL[2][64 * KBLK];  // 2x8 KB
    __shared__ __attribute__((aligned(16))) unsigned short Pq[4 * 4 * 16 * 16]; // 8 KB [w][s4][row][col]

    const int tid  = threadIdx.x;
    const int lane = tid & 63;
    const int w    = tid >> 6;
    // XCD-grouped decode: xcd = F&7 keeps all 32 q-blocks of a bh on one XCD;
    // qb descending => heavy blocks dispatch first.
    const int F   = blockIdx.x;
    const int xcd = F & 7;
    const int r_  = F >> 3;
    const int qb  = 31 - (r_ & 31);
    const int bh  = xcd | ((r_ >> 5) << 3);
    const int b = bh >> 4, h = bh & 15;
    const int q0 = qb * QBLK;
    const int lg = lane >> 4;
    const int lr = lane & 15;

    const size_t tokbase = (size_t)b * SEQ;
    const size_t hoff = (size_t)h * D_HEAD;

    const int crow  = lane >> 3;
    const int uslot = (lane & 7) ^ crow;

    // Q fragments (Q pre-scaled by 0.125*log2e at projection)
    const short* Qp = (const short*)Q + (tokbase + q0 + w * 16 + lr) * D_MODEL + hoff + lg * 8;
    const short8 qf0 = *(const short8*)(Qp);
    const short8 qf1 = *(const short8*)(Qp + 32);

    // hoisted swizzled LDS fragment offsets (shorts); same for K and V tiles
    int koff[2][4];
    #pragma unroll
    for (int hh = 0; hh < 2; ++hh)
        #pragma unroll
        for (int s4 = 0; s4 < 4; ++s4)
            koff[hh][s4] = (s4 * 16 + lr) * 64 + (((hh * 4 + lg) ^ (lr & 7)) * 8);
    // P offsets: write (w,s4,row=lg*4+i,col=lr); read (sub=c2*2+(lg>>1), row=lr, col=(lg&1)*8)
    const int pwbase = (w * 4) * 256 + (lg * 4) * 16 + lr;
    int prd[2];
    #pragma unroll
    for (int c2 = 0; c2 < 2; ++c2)
        prd[c2] = (w * 4 + c2 * 2 + (lg >> 1)) * 256 + lr * 16 + (lg & 1) * 8;

    float m[4], l[4];
    f32x4 acc[4];
    #pragma unroll
    for (int i = 0; i < 4; ++i) { m[i] = -INFINITY; l[i] = 0.f; acc[i] = (f32x4){0.f,0.f,0.f,0.f}; }

    const int ntiles = qb + 1;

    // prologue: stage tile 0 into buf 0
    {
        #pragma unroll
        for (int i = 0; i < 2; ++i) {
            const int c = w * 2 + i;
            const int row = c * 8 + crow;
            gload16(K + (tokbase + row) * D_MODEL + hoff + uslot * 8, &KtL[0][c * 512]);
            gload16(Vt + ((size_t)bh * 64 + row) * SEQ + uslot * 8, &VsL[0][c * 512]);
        }
    }
    __syncthreads();

    int cur = 0;
    for (int t = 0; t < ntiles; ++t) {
        // issue next tile's loads into the other buffer (fly during compute)
        if (t + 1 < ntiles) {
            const int k1 = (t + 1) * KBLK;
            #pragma unroll
            for (int i = 0; i < 2; ++i) {
                const int c = w * 2 + i;
                const int row = c * 8 + crow;
                gload16(K + (tokbase + k1 + row) * D_MODEL + hoff + uslot * 8, &KtL[cur ^ 1][c * 512]);
                gload16(Vt + ((size_t)bh * 64 + row) * SEQ + k1 + uslot * 8, &VsL[cur ^ 1][c * 512]);
            }
        }
        const unsigned short* Kc = KtL[cur];
        const unsigned short* Vc = VsL[cur];

        // QK^T (scores already in exp2 domain via Q pre-scale)
        f32x4 sc[4];
        #pragma unroll
        for (int s4 = 0; s4 < 4; ++s4) {
            const short8 kf0 = *(const short8*)(Kc + koff[0][s4]);
            const short8 kf1 = *(const short8*)(Kc + koff[1][s4]);
            f32x4 z = {0.f, 0.f, 0.f, 0.f};
            z = __builtin_amdgcn_mfma_f32_16x16x32_bf16(qf0, kf0, z, 0, 0, 0);
            z = __builtin_amdgcn_mfma_f32_16x16x32_bf16(qf1, kf1, z, 0, 0, 0);
            sc[s4] = z;
        }

        // causal mask: only the diagonal tile needs it (wave-uniform branch)
        if (t == qb) {
            const int qr = w * 16 + lg * 4;
            #pragma unroll
            for (int s4 = 0; s4 < 4; ++s4) {
                const int kk = s4 * 16 + lr;
                #pragma unroll
                for (int i = 0; i < 4; ++i)
                    sc[s4][i] = (kk <= qr + i) ? sc[s4][i] : -INFINITY;
            }
        }

        // online softmax (exp2 domain)
        float c_[4];
        #pragma unroll
        for (int i = 0; i < 4; ++i) {
            float rm = fmaxf(fmaxf(sc[0][i], sc[1][i]), fmaxf(sc[2][i], sc[3][i]));
            rm = fmaxf(rm, __shfl_xor(rm, 1));
            rm = fmaxf(rm, __shfl_xor(rm, 2));
            rm = fmaxf(rm, __shfl_xor(rm, 4));
            rm = fmaxf(rm, __shfl_xor(rm, 8));
            const float mn = fmaxf(m[i], rm);
            c_[i] = __builtin_exp2f(m[i] - mn);
            m[i] = mn;
        }
        #pragma unroll
        for (int i = 0; i < 4; ++i) {
            float rs = 0.f;
            #pragma unroll
            for (int s4 = 0; s4 < 4; ++s4) {
                const float p = __builtin_exp2f(sc[s4][i] - m[i]);
                sc[s4][i] = p;
                rs += p;
            }
            rs += __shfl_xor(rs, 1); rs += __shfl_xor(rs, 2);
            rs += __shfl_xor(rs, 4); rs += __shfl_xor(rs, 8);
            l[i] = l[i] * c_[i] + rs;
            #pragma unroll
            for (int ds = 0; ds < 4; ++ds) acc[ds][i] *= c_[i];
        }

        // P -> LDS (round-half-up to bf16: 2 VALU/elem), then PV
        #pragma unroll
        for (int s4 = 0; s4 < 4; ++s4)
            #pragma unroll
            for (int i = 0; i < 4; ++i) {
                const unsigned u = __float_as_uint(sc[s4][i]) + 0x8000u;
                Pq[pwbase + s4 * 256 + i * 16] = (unsigned short)(u >> 16);
            }

        #pragma unroll
        for (int c2 = 0; c2 < 2; ++c2) {
            const short8 pf = *(const short8*)(Pq + prd[c2]);
            #pragma unroll
            for (int ds = 0; ds < 4; ++ds) {
                const short8 vf = *(const short8*)(Vc + koff[c2][ds]);
                acc[ds] = __builtin_amdgcn_mfma_f32_16x16x32_bf16(pf, vf, acc[ds], 0, 0, 0);
            }
        }

        __syncthreads();     // drains next-tile loads; protects both LDS buffers
        cur ^= 1;
    }

    const int gq = q0 + w * 16 + lg * 4;
    #pragma unroll
    for (int ds = 0; ds < 4; ++ds) {
        const float inv = 1.0f;   // placeholder to keep structure clear
        #pragma unroll
        for (int i = 0; i < 4; ++i) {
            const float o = acc[ds][i] / l[i];
            Mo[(tokbase + gq + i) * D_MODEL + hoff + ds * 16 + lr] = f2bf(o);
        }
        (void)inv;
    }
}

extern "C" void kernel_launch(void* const* d_in, const int* in_sizes, int n_in,
                              void* d_out, int out_size, void* d_ws, size_t ws_size,
                              hipStream_t stream) {
    const float* X  = (const float*)d_in[0];
    const float* lg = (const float*)d_in[1];
    const float* lb = (const float*)d_in[2];
    const float* Wq = (const float*)d_in[3];
    const float* bq = (const float*)d_in[4];
    const float* Wk = (const float*)d_in[5];
    const float* bk = (const float*)d_in[6];
    const float* Wv = (const float*)d_in[7];
    const float* bv = (const float*)d_in[8];
    const float* Wo = (const float*)d_in[9];
    const float* bo = (const float*)d_in[10];
    float* out = (float*)d_out;

    char* ws = (char*)d_ws;
    const size_t MB = 1024 * 1024;
    unsigned short* Xn  = (unsigned short*)(ws + 0);          // 16 MB
    unsigned short* WqB = (unsigned short*)(ws + 16 * MB);    // 2 MB each
    unsigned short* WkB = (unsigned short*)(ws + 18 * MB);
    unsigned short* WvB = (unsigned short*)(ws + 20 * MB);
    unsigned short* WoB = (unsigned short*)(ws + 22 * MB);
    unsigned short* Qb  = (unsigned short*)(ws + 24 * MB);    // 16 MB each
    unsigned short* Kb  = (unsigned short*)(ws + 40 * MB);
    unsigned short* Vb  = (unsigned short*)(ws + 56 * MB);    // raw V (dead after transpose)
    unsigned short* Vtg = (unsigned short*)(ws + 72 * MB);    // V^T [b*D+n][s]
    unsigned short* Mb  = (unsigned short*)(ws + 56 * MB);    // merged AV, overwrites Vb

    // 1. LayerNorm -> Xn (bf16)
    ln_kernel<<<TOKENS, 256, 0, stream>>>(X, lg, lb, Xn);

    // 2. weights f32 -> bf16
    cvt_kernel<<<1024, 256, 0, stream>>>(Wq, WqB);
    cvt_kernel<<<1024, 256, 0, stream>>>(Wk, WkB);
    cvt_kernel<<<1024, 256, 0, stream>>>(Wv, WvB);
    cvt_kernel<<<1024, 256, 0, stream>>>(Wo, WoB);

    // 3. Q/K/V projections (Q folded with 0.125*log2e for exp2-domain softmax)
    dim3 ggrid(D_MODEL / 128, TOKENS / 128);
    const float qscale = 0.125f * 1.44269504088896f;
    gemm128<true><<<ggrid, 256, 0, stream>>>(Xn, WqB, bq, Qb, TOKENS, D_MODEL, D_MODEL, qscale);
    gemm128<true><<<ggrid, 256, 0, stream>>>(Xn, WkB, bk, Kb, TOKENS, D_MODEL, D_MODEL, 1.0f);
    gemm128<true><<<ggrid, 256, 0, stream>>>(Xn, WvB, bv, Vb, TOKENS, D_MODEL, D_MODEL, 1.0f);

    // 3b. V -> V^T
    dim3 tgrid(SEQ / 64, D_MODEL / 64, BATCH);
    transpose_v<<<tgrid, 256, 0, stream>>>(Vb, Vtg);

    // 4. MFMA causal flash attention (1D XCD-grouped grid)
    flash_attn<<<(SEQ / QBLK) * BATCH * N_HEADS, 256, 0, stream>>>(Qb, Kb, Vtg, Mb);

    // 5. output projection -> d_out (f32)
    gemm128<false><<<ggrid, 256, 0, stream>>>(Mb, WoB, bo, out, TOKENS, D_MODEL, D_MODEL, 1.0f);
}

// Round 7
// 359.240 us; speedup vs baseline: 27.8154x; 1.0401x over previous
//
#include <hip/hip_runtime.h>

#define D_MODEL 1024
#define N_HEADS 16
#define D_HEAD 64
#define BATCH 4
#define SEQ 2048
#define TOKENS (BATCH * SEQ)   // 8192
#define D_QKV 3072             // fused Q|K|V width

#define QBLK 64
#define KBLK 64

typedef __attribute__((ext_vector_type(8))) short short8;
typedef __attribute__((ext_vector_type(4))) float f32x4;

__device__ __forceinline__ unsigned short f2bf(float f) {
    unsigned u = __float_as_uint(f);
    u += 0x7fffu + ((u >> 16) & 1u);   // round-to-nearest-even
    return (unsigned short)(u >> 16);
}
__device__ __forceinline__ void gload16(const unsigned short* g, unsigned short* lds) {
    __builtin_amdgcn_global_load_lds((const __attribute__((address_space(1))) void*)g,
                                     (__attribute__((address_space(3))) void*)lds, 16, 0, 0);
}

// ---------------- LayerNorm: one block (256 thr) per token, f32 -> bf16 ----------------
__global__ void ln_kernel(const float* __restrict__ X, const float* __restrict__ gamma,
                          const float* __restrict__ beta, unsigned short* __restrict__ Xn) {
    const int t = blockIdx.x;
    const int tid = threadIdx.x;                      // 0..255
    const float4 v = ((const float4*)(X + (size_t)t * D_MODEL))[tid];
    float s  = v.x + v.y + v.z + v.w;
    float s2 = v.x * v.x + v.y * v.y + v.z * v.z + v.w * v.w;
    for (int off = 32; off > 0; off >>= 1) {
        s  += __shfl_xor(s,  off);
        s2 += __shfl_xor(s2, off);
    }
    __shared__ float sh[8];
    const int wv = tid >> 6;
    if ((tid & 63) == 0) { sh[wv] = s; sh[4 + wv] = s2; }
    __syncthreads();
    const float ts  = sh[0] + sh[1] + sh[2] + sh[3];
    const float ts2 = sh[4] + sh[5] + sh[6] + sh[7];
    const float mu  = ts * (1.0f / D_MODEL);
    const float var = ts2 * (1.0f / D_MODEL) - mu * mu;
    const float rs  = rsqrtf(var + 1e-5f);
    const float4 gm = ((const float4*)gamma)[tid];
    const float4 bt = ((const float4*)beta)[tid];
    ushort4 o;
    o.x = f2bf((v.x - mu) * rs * gm.x + bt.x);
    o.y = f2bf((v.y - mu) * rs * gm.y + bt.y);
    o.z = f2bf((v.z - mu) * rs * gm.z + bt.z);
    o.w = f2bf((v.w - mu) * rs * gm.w + bt.w);
    ((ushort4*)Xn)[(size_t)t * (D_MODEL / 4) + tid] = o;
}

// ---------------- fused weight convert: Wq|Wk|Wv -> Wqkv rows, Wo -> WoB ----------------
// 1048576 threads, one float4 each: matrix = i>>18, elem = i&262143.
__global__ void cvt_all(const float* __restrict__ Wq, const float* __restrict__ Wk,
                        const float* __restrict__ Wv, const float* __restrict__ Wo,
                        unsigned short* __restrict__ Wqkv, unsigned short* __restrict__ WoB) {
    const int i = blockIdx.x * blockDim.x + threadIdx.x;
    const int mtx  = i >> 18;
    const int elem = i & 262143;
    const float* src;
    unsigned short* dst;
    if (mtx == 0)      { src = Wq; dst = Wqkv; }
    else if (mtx == 1) { src = Wk; dst = Wqkv + (1 << 20); }
    else if (mtx == 2) { src = Wv; dst = Wqkv + (2 << 20); }
    else               { src = Wo; dst = WoB; }
    const float4 v = ((const float4*)src)[elem];
    ushort4 o;
    o.x = f2bf(v.x); o.y = f2bf(v.y); o.z = f2bf(v.z); o.w = f2bf(v.w);
    ((ushort4*)dst)[elem] = o;
}

// ---------------- coalesced transpose of the V-part of QKV -> V^T [bh*64+d][s] ----------------
__global__ void transpose_v(const unsigned short* __restrict__ QKV, unsigned short* __restrict__ out) {
    __shared__ __attribute__((aligned(16))) unsigned short T[64][72];
    const int tid = threadIdx.x;
    const int s0 = blockIdx.x * 64;
    const int n0 = blockIdx.y * 64;
    const int b  = blockIdx.z;
    const int r = tid >> 2, c = (tid & 3) * 16;
    const unsigned short* ip = QKV + ((size_t)(b * SEQ + s0 + r)) * D_QKV + 2048 + n0 + c;
    *(short8*)&T[r][c]     = *(const short8*)ip;
    *(short8*)&T[r][c + 8] = *(const short8*)(ip + 8);
    __syncthreads();
    unsigned short* op = out + ((size_t)(b * D_MODEL + n0 + r)) * SEQ + s0 + c;
    short8 o0, o1;
    #pragma unroll
    for (int j = 0; j < 8; ++j) { o0[j] = (short)T[c + j][r]; o1[j] = (short)T[c + 8 + j][r]; }
    *(short8*)op       = o0;
    *(short8*)(op + 8) = o1;
}

// ---------------- 128x128-tile NT GEMM, 2-phase double-buffered ----------------
// C[M,N] = (A[M,K] * B[N,K]^T + bias_seg) * oscale_seg.  BK=64, 4 waves 2x2.
// seg = blockIdx.x>>3 picks bias pointer (Q|K|V segments of a fused B).
// Prefetch of tile t+1 flies during compute of tile t; one barrier per tile.
template <bool OUT_BF16>
__global__ __launch_bounds__(256) void gemm128(const unsigned short* __restrict__ A,
                                               const unsigned short* __restrict__ B,
                                               const float* __restrict__ b0,
                                               const float* __restrict__ b1,
                                               const float* __restrict__ b2,
                                               void* __restrict__ out,
                                               int M, int N, int K, float qscale) {
    __shared__ __attribute__((aligned(16))) unsigned short As[2][128 * 64];   // 32 KB
    __shared__ __attribute__((aligned(16))) unsigned short Bs[2][128 * 64];   // 32 KB
    const int tid  = threadIdx.x;
    const int lane = tid & 63;
    const int w    = tid >> 6;
    const int wm = w >> 1, wn = w & 1;
    const int m0 = blockIdx.y * 128;
    const int n0 = blockIdx.x * 128;
    const int lr = lane & 15, lg = lane >> 4;

    const int crow  = lane >> 3;          // 0..7
    const int uslot = (lane & 7) ^ crow;  // inverse-swizzled source slot

    const unsigned short* Ab = A + (size_t)m0 * K + uslot * 8;
    const unsigned short* Bb = B + (size_t)n0 * K + uslot * 8;

    // prologue: stage k-tile 0 into buf 0
    #pragma unroll
    for (int i = 0; i < 4; ++i) {
        const int c = w * 4 + i;
        const int grow = c * 8 + crow;
        gload16(Ab + (size_t)grow * K, &As[0][c * 512]);
        gload16(Bb + (size_t)grow * K, &Bs[0][c * 512]);
    }
    __syncthreads();

    f32x4 acc[4][4] = {};
    const int NT = K >> 6;
    int cur = 0;
    for (int kt = 0; kt < NT; ++kt) {
        if (kt + 1 < NT) {
            const int k1 = (kt + 1) << 6;
            #pragma unroll
            for (int i = 0; i < 4; ++i) {
                const int c = w * 4 + i;
                const int grow = c * 8 + crow;
                gload16(Ab + (size_t)grow * K + k1, &As[cur ^ 1][c * 512]);
                gload16(Bb + (size_t)grow * K + k1, &Bs[cur ^ 1][c * 512]);
            }
        }
        #pragma unroll
        for (int h = 0; h < 2; ++h) {
            short8 af[4], bf[4];
            #pragma unroll
            for (int mi = 0; mi < 4; ++mi) {
                const int row = wm * 64 + mi * 16 + lr;
                const int slot = (h * 4 + lg) ^ (row & 7);
                af[mi] = *(const short8*)(&As[cur][row * 64 + slot * 8]);
            }
            #pragma unroll
            for (int ni = 0; ni < 4; ++ni) {
                const int row = wn * 64 + ni * 16 + lr;
                const int slot = (h * 4 + lg) ^ (row & 7);
                bf[ni] = *(const short8*)(&Bs[cur][row * 64 + slot * 8]);
            }
            #pragma unroll
            for (int mi = 0; mi < 4; ++mi)
                #pragma unroll
                for (int ni = 0; ni < 4; ++ni)
                    acc[mi][ni] = __builtin_amdgcn_mfma_f32_16x16x32_bf16(af[mi], bf[ni], acc[mi][ni], 0, 0, 0);
        }
        __syncthreads();
        cur ^= 1;
    }

    const int seg = blockIdx.x >> 3;                 // 0=Q,1=K,2=V segment
    const float* bp = (seg == 0) ? b0 : (seg == 1) ? b1 : b2;
    const float osc = (seg == 0) ? qscale : 1.0f;
    #pragma unroll
    for (int ni = 0; ni < 4; ++ni) {
        const int n = n0 + wn * 64 + ni * 16 + lr;
        const float bv = bp[n & 1023];
        #pragma unroll
        for (int mi = 0; mi < 4; ++mi) {
            const int mb = m0 + wm * 64 + mi * 16 + lg * 4;
            #pragma unroll
            for (int i = 0; i < 4; ++i) {
                const float val = (acc[mi][ni][i] + bv) * osc;
                if (OUT_BF16) ((unsigned short*)out)[(size_t)(mb + i) * N + n] = f2bf(val);
                else          ((float*)out)[(size_t)(mb + i) * N + n] = val;
            }
        }
    }
}

// ---------------- MFMA causal flash attention, 2-phase pipelined ----------------
// 1D XCD-grouped grid; Q/K read from fused QKV (stride 3072); exp2-domain
// softmax with defer-max (THR=8); padded P tile (48B row stride);
// setprio(1) around MFMA clusters.
__global__ __launch_bounds__(256) void flash_attn(const unsigned short* __restrict__ QKV,
                                                  const unsigned short* __restrict__ Vt,
                                                  unsigned short* __restrict__ Mo) {
    __shared__ __attribute__((aligned(16))) unsigned short KtL[2][KBLK * 64];  // 16 KB
    __shared__ __attribute__((aligned(16))) unsigned short VsL[2][64 * KBLK];  // 16 KB
    __shared__ __attribute__((aligned(16))) unsigned short Pq[4 * 4 * 16 * 24]; // 12 KB

    const int tid  = threadIdx.x;
    const int lane = tid & 63;
    const int w    = tid >> 6;
    const int F   = blockIdx.x;
    const int xcd = F & 7;
    const int r_  = F >> 3;
    const int qb  = 31 - (r_ & 31);
    const int bh  = xcd | ((r_ >> 5) << 3);
    const int b = bh >> 4, h = bh & 15;
    const int q0 = qb * QBLK;
    const int lg = lane >> 4;
    const int lr = lane & 15;

    const size_t tokbase = (size_t)b * SEQ;
    const size_t hoff = (size_t)h * D_HEAD;

    const int crow  = lane >> 3;
    const int uslot = (lane & 7) ^ crow;

    // Q fragments (Q pre-scaled by 0.125*log2e at projection)
    const short* Qp = (const short*)QKV + (tokbase + q0 + w * 16 + lr) * D_QKV + hoff + lg * 8;
    const short8 qf0 = *(const short8*)(Qp);
    const short8 qf1 = *(const short8*)(Qp + 32);

    const unsigned short* Kg = QKV + (tokbase) * D_QKV + 1024 + hoff + uslot * 8;  // + row*D_QKV
    const unsigned short* Vg = Vt + ((size_t)bh * 64) * SEQ + uslot * 8;           // + row*SEQ

    // hoisted swizzled LDS fragment offsets
    int koff[2][4];
    #pragma unroll
    for (int hh = 0; hh < 2; ++hh)
        #pragma unroll
        for (int s4 = 0; s4 < 4; ++s4)
            koff[hh][s4] = (s4 * 16 + lr) * 64 + (((hh * 4 + lg) ^ (lr & 7)) * 8);
    // P (padded rows: 24 shorts): write (s4,row=lg*4+i,col=lr), read subtile c2*2+(lg>>1)
    const int pwbase = w * 1536 + lg * 96 + lr;
    int prd[2];
    #pragma unroll
    for (int c2 = 0; c2 < 2; ++c2)
        prd[c2] = w * 1536 + (c2 * 2 + (lg >> 1)) * 384 + lr * 24 + (lg & 1) * 8;

    float m[4], l[4];
    f32x4 acc[4];
    #pragma unroll
    for (int i = 0; i < 4; ++i) { m[i] = -INFINITY; l[i] = 0.f; acc[i] = (f32x4){0.f,0.f,0.f,0.f}; }

    const int ntiles = qb + 1;

    // prologue: stage tile 0 into buf 0
    #pragma unroll
    for (int i = 0; i < 2; ++i) {
        const int c = w * 2 + i;
        const int row = c * 8 + crow;
        gload16(Kg + (size_t)row * D_QKV, &KtL[0][c * 512]);
        gload16(Vg + (size_t)row * SEQ, &VsL[0][c * 512]);
    }
    __syncthreads();

    int cur = 0;
    for (int t = 0; t < ntiles; ++t) {
        if (t + 1 < ntiles) {
            const int k1 = (t + 1) * KBLK;
            #pragma unroll
            for (int i = 0; i < 2; ++i) {
                const int c = w * 2 + i;
                const int row = c * 8 + crow;
                gload16(Kg + (size_t)(k1 + row) * D_QKV, &KtL[cur ^ 1][c * 512]);
                gload16(Vg + (size_t)row * SEQ + k1, &VsL[cur ^ 1][c * 512]);
            }
        }
        const unsigned short* Kc = KtL[cur];
        const unsigned short* Vc = VsL[cur];

        // QK^T (exp2 domain)
        f32x4 sc[4];
        __builtin_amdgcn_s_setprio(1);
        #pragma unroll
        for (int s4 = 0; s4 < 4; ++s4) {
            const short8 kf0 = *(const short8*)(Kc + koff[0][s4]);
            const short8 kf1 = *(const short8*)(Kc + koff[1][s4]);
            f32x4 z = {0.f, 0.f, 0.f, 0.f};
            z = __builtin_amdgcn_mfma_f32_16x16x32_bf16(qf0, kf0, z, 0, 0, 0);
            z = __builtin_amdgcn_mfma_f32_16x16x32_bf16(qf1, kf1, z, 0, 0, 0);
            sc[s4] = z;
        }
        __builtin_amdgcn_s_setprio(0);

        // causal mask on the diagonal tile only (wave-uniform)
        if (t == qb) {
            const int qr = w * 16 + lg * 4;
            #pragma unroll
            for (int s4 = 0; s4 < 4; ++s4) {
                const int kk = s4 * 16 + lr;
                #pragma unroll
                for (int i = 0; i < 4; ++i)
                    sc[s4][i] = (kk <= qr + i) ? sc[s4][i] : -INFINITY;
            }
        }

        // row max + defer-max vote
        float rm[4];
        bool need = false;
        #pragma unroll
        for (int i = 0; i < 4; ++i) {
            float r = fmaxf(fmaxf(sc[0][i], sc[1][i]), fmaxf(sc[2][i], sc[3][i]));
            r = fmaxf(r, __shfl_xor(r, 1));
            r = fmaxf(r, __shfl_xor(r, 2));
            r = fmaxf(r, __shfl_xor(r, 4));
            r = fmaxf(r, __shfl_xor(r, 8));
            rm[i] = r;
            need |= (r > m[i] + 8.0f);
        }
        if (__any(need)) {    // rescale path
            #pragma unroll
            for (int i = 0; i < 4; ++i) {
                const float mn = fmaxf(m[i], rm[i]);
                const float c  = __builtin_exp2f(m[i] - mn);
                m[i] = mn;
                l[i] *= c;
                #pragma unroll
                for (int ds = 0; ds < 4; ++ds) acc[ds][i] *= c;
            }
        }

        // p = exp2(s - m), row sums, P -> LDS
        #pragma unroll
        for (int i = 0; i < 4; ++i) {
            float rs = 0.f;
            #pragma unroll
            for (int s4 = 0; s4 < 4; ++s4) {
                const float p = __builtin_exp2f(sc[s4][i] - m[i]);
                sc[s4][i] = p;
                rs += p;
            }
            rs += __shfl_xor(rs, 1); rs += __shfl_xor(rs, 2);
            rs += __shfl_xor(rs, 4); rs += __shfl_xor(rs, 8);
            l[i] += rs;
        }
        #pragma unroll
        for (int s4 = 0; s4 < 4; ++s4)
            #pragma unroll
            for (int i = 0; i < 4; ++i) {
                const unsigned u = __float_as_uint(sc[s4][i]) + 0x8000u;  // round-half-up
                Pq[pwbase + s4 * 384 + i * 24] = (unsigned short)(u >> 16);
            }

        // PV
        __builtin_amdgcn_s_setprio(1);
        #pragma unroll
        for (int c2 = 0; c2 < 2; ++c2) {
            const short8 pf = *(const short8*)(Pq + prd[c2]);
            #pragma unroll
            for (int ds = 0; ds < 4; ++ds) {
                const short8 vf = *(const short8*)(Vc + koff[c2][ds]);
                acc[ds] = __builtin_amdgcn_mfma_f32_16x16x32_bf16(pf, vf, acc[ds], 0, 0, 0);
            }
        }
        __builtin_amdgcn_s_setprio(0);

        __syncthreads();     // drains next-tile loads; protects LDS buffers
        cur ^= 1;
    }

    const int gq = q0 + w * 16 + lg * 4;
    #pragma unroll
    for (int ds = 0; ds < 4; ++ds) {
        #pragma unroll
        for (int i = 0; i < 4; ++i) {
            const float o = acc[ds][i] / l[i];
            Mo[(tokbase + gq + i) * D_MODEL + hoff + ds * 16 + lr] = f2bf(o);
        }
    }
}

extern "C" void kernel_launch(void* const* d_in, const int* in_sizes, int n_in,
                              void* d_out, int out_size, void* d_ws, size_t ws_size,
                              hipStream_t stream) {
    const float* X  = (const float*)d_in[0];
    const float* lg = (const float*)d_in[1];
    const float* lb = (const float*)d_in[2];
    const float* Wq = (const float*)d_in[3];
    const float* bq = (const float*)d_in[4];
    const float* Wk = (const float*)d_in[5];
    const float* bk = (const float*)d_in[6];
    const float* Wv = (const float*)d_in[7];
    const float* bv = (const float*)d_in[8];
    const float* Wo = (const float*)d_in[9];
    const float* bo = (const float*)d_in[10];
    float* out = (float*)d_out;

    char* ws = (char*)d_ws;
    const size_t MB = 1024 * 1024;
    unsigned short* Xn   = (unsigned short*)(ws + 0);          // 16 MB (LN out; dead after QKV gemm)
    unsigned short* Vtg  = (unsigned short*)(ws + 0);          // V^T reuses Xn slot
    unsigned short* Wqkv = (unsigned short*)(ws + 16 * MB);    // 6 MB fused [3072][1024]
    unsigned short* WoB  = (unsigned short*)(ws + 22 * MB);    // 2 MB
    unsigned short* QKVb = (unsigned short*)(ws + 24 * MB);    // 48 MB [8192][3072]
    unsigned short* Mb   = (unsigned short*)(ws + 72 * MB);    // 16 MB merged AV

    // 1. LayerNorm -> Xn (bf16)
    ln_kernel<<<TOKENS, 256, 0, stream>>>(X, lg, lb, Xn);

    // 2. fused weight convert (Wq|Wk|Wv -> Wqkv, Wo -> WoB)
    cvt_all<<<4096, 256, 0, stream>>>(Wq, Wk, Wv, Wo, Wqkv, WoB);

    // 3. fused QKV projection: [8192,1024] x [3072,1024]^T -> [8192,3072]
    //    Q-segment scaled by 0.125*log2e (exp2-domain softmax)
    const float qscale = 0.125f * 1.44269504088896f;
    dim3 qkvgrid(D_QKV / 128, TOKENS / 128);
    gemm128<true><<<qkvgrid, 256, 0, stream>>>(Xn, Wqkv, bq, bk, bv, QKVb,
                                               TOKENS, D_QKV, D_MODEL, qscale);

    // 3b. V-part of QKV -> V^T (overwrites Xn slot)
    dim3 tgrid(SEQ / 64, D_MODEL / 64, BATCH);
    transpose_v<<<tgrid, 256, 0, stream>>>(QKVb, Vtg);

    // 4. MFMA causal flash attention (1D XCD-grouped grid)
    flash_attn<<<(SEQ / QBLK) * BATCH * N_HEADS, 256, 0, stream>>>(QKVb, Vtg, Mb);

    // 5. output projection -> d_out (f32)
    dim3 ogrid(D_MODEL / 128, TOKENS / 128);
    gemm128<false><<<ogrid, 256, 0, stream>>>(Mb, WoB, bo, bo, bo, out,
                                              TOKENS, D_MODEL, D_MODEL, 1.0f);
}

// Round 8
// 310.845 us; speedup vs baseline: 32.1459x; 1.1557x over previous
//
#include <hip/hip_runtime.h>

#define D_MODEL 1024
#define N_HEADS 16
#define D_HEAD 64
#define BATCH 4
#define SEQ 2048
#define TOKENS (BATCH * SEQ)   // 8192
#define D_QKV 3072             // fused Q|K|V width

#define QBLK 64
#define KBLK 64

typedef __attribute__((ext_vector_type(8))) short short8;
typedef __attribute__((ext_vector_type(4))) float f32x4;

__device__ __forceinline__ unsigned short f2bf(float f) {
    unsigned u = __float_as_uint(f);
    u += 0x7fffu + ((u >> 16) & 1u);   // round-to-nearest-even
    return (unsigned short)(u >> 16);
}
__device__ __forceinline__ void gload16(const unsigned short* g, unsigned short* lds) {
    __builtin_amdgcn_global_load_lds((const __attribute__((address_space(1))) void*)g,
                                     (__attribute__((address_space(3))) void*)lds, 16, 0, 0);
}

// ---------------- LayerNorm: one block (256 thr) per token, f32 -> bf16 ----------------
__global__ void ln_kernel(const float* __restrict__ X, const float* __restrict__ gamma,
                          const float* __restrict__ beta, unsigned short* __restrict__ Xn) {
    const int t = blockIdx.x;
    const int tid = threadIdx.x;                      // 0..255
    const float4 v = ((const float4*)(X + (size_t)t * D_MODEL))[tid];
    float s  = v.x + v.y + v.z + v.w;
    float s2 = v.x * v.x + v.y * v.y + v.z * v.z + v.w * v.w;
    for (int off = 32; off > 0; off >>= 1) {
        s  += __shfl_xor(s,  off);
        s2 += __shfl_xor(s2, off);
    }
    __shared__ float sh[8];
    const int wv = tid >> 6;
    if ((tid & 63) == 0) { sh[wv] = s; sh[4 + wv] = s2; }
    __syncthreads();
    const float ts  = sh[0] + sh[1] + sh[2] + sh[3];
    const float ts2 = sh[4] + sh[5] + sh[6] + sh[7];
    const float mu  = ts * (1.0f / D_MODEL);
    const float var = ts2 * (1.0f / D_MODEL) - mu * mu;
    const float rs  = rsqrtf(var + 1e-5f);
    const float4 gm = ((const float4*)gamma)[tid];
    const float4 bt = ((const float4*)beta)[tid];
    ushort4 o;
    o.x = f2bf((v.x - mu) * rs * gm.x + bt.x);
    o.y = f2bf((v.y - mu) * rs * gm.y + bt.y);
    o.z = f2bf((v.z - mu) * rs * gm.z + bt.z);
    o.w = f2bf((v.w - mu) * rs * gm.w + bt.w);
    ((ushort4*)Xn)[(size_t)t * (D_MODEL / 4) + tid] = o;
}

// ---------------- fused weight convert: Wq|Wk|Wv -> Wqkv rows, Wo -> WoB ----------------
__global__ void cvt_all(const float* __restrict__ Wq, const float* __restrict__ Wk,
                        const float* __restrict__ Wv, const float* __restrict__ Wo,
                        unsigned short* __restrict__ Wqkv, unsigned short* __restrict__ WoB) {
    const int i = blockIdx.x * blockDim.x + threadIdx.x;
    const int mtx  = i >> 18;
    const int elem = i & 262143;
    const float* src;
    unsigned short* dst;
    if (mtx == 0)      { src = Wq; dst = Wqkv; }
    else if (mtx == 1) { src = Wk; dst = Wqkv + (1 << 20); }
    else if (mtx == 2) { src = Wv; dst = Wqkv + (2 << 20); }
    else               { src = Wo; dst = WoB; }
    const float4 v = ((const float4*)src)[elem];
    ushort4 o;
    o.x = f2bf(v.x); o.y = f2bf(v.y); o.z = f2bf(v.z); o.w = f2bf(v.w);
    ((ushort4*)dst)[elem] = o;
}

// ---------------- coalesced transpose of the V-part of QKV -> V^T [bh*64+d][s] ----------------
__global__ void transpose_v(const unsigned short* __restrict__ QKV, unsigned short* __restrict__ out) {
    __shared__ __attribute__((aligned(16))) unsigned short T[64][72];
    const int tid = threadIdx.x;
    const int s0 = blockIdx.x * 64;
    const int n0 = blockIdx.y * 64;
    const int b  = blockIdx.z;
    const int r = tid >> 2, c = (tid & 3) * 16;
    const unsigned short* ip = QKV + ((size_t)(b * SEQ + s0 + r)) * D_QKV + 2048 + n0 + c;
    *(short8*)&T[r][c]     = *(const short8*)ip;
    *(short8*)&T[r][c + 8] = *(const short8*)(ip + 8);
    __syncthreads();
    unsigned short* op = out + ((size_t)(b * D_MODEL + n0 + r)) * SEQ + s0 + c;
    short8 o0, o1;
    #pragma unroll
    for (int j = 0; j < 8; ++j) { o0[j] = (short)T[c + j][r]; o1[j] = (short)T[c + 8 + j][r]; }
    *(short8*)op       = o0;
    *(short8*)(op + 8) = o1;
}

// ---------------- 128x128-tile NT GEMM, 2-phase double-buffered ----------------
template <bool OUT_BF16>
__global__ __launch_bounds__(256) void gemm128(const unsigned short* __restrict__ A,
                                               const unsigned short* __restrict__ B,
                                               const float* __restrict__ b0,
                                               const float* __restrict__ b1,
                                               const float* __restrict__ b2,
                                               void* __restrict__ out,
                                               int M, int N, int K, float qscale) {
    __shared__ __attribute__((aligned(16))) unsigned short As[2][128 * 64];   // 32 KB
    __shared__ __attribute__((aligned(16))) unsigned short Bs[2][128 * 64];   // 32 KB
    const int tid  = threadIdx.x;
    const int lane = tid & 63;
    const int w    = tid >> 6;
    const int wm = w >> 1, wn = w & 1;
    const int m0 = blockIdx.y * 128;
    const int n0 = blockIdx.x * 128;
    const int lr = lane & 15, lg = lane >> 4;

    const int crow  = lane >> 3;          // 0..7
    const int uslot = (lane & 7) ^ crow;  // inverse-swizzled source slot

    const unsigned short* Ab = A + (size_t)m0 * K + uslot * 8;
    const unsigned short* Bb = B + (size_t)n0 * K + uslot * 8;

    #pragma unroll
    for (int i = 0; i < 4; ++i) {
        const int c = w * 4 + i;
        const int grow = c * 8 + crow;
        gload16(Ab + (size_t)grow * K, &As[0][c * 512]);
        gload16(Bb + (size_t)grow * K, &Bs[0][c * 512]);
    }
    __syncthreads();

    f32x4 acc[4][4] = {};
    const int NT = K >> 6;
    int cur = 0;
    for (int kt = 0; kt < NT; ++kt) {
        if (kt + 1 < NT) {
            const int k1 = (kt + 1) << 6;
            #pragma unroll
            for (int i = 0; i < 4; ++i) {
                const int c = w * 4 + i;
                const int grow = c * 8 + crow;
                gload16(Ab + (size_t)grow * K + k1, &As[cur ^ 1][c * 512]);
                gload16(Bb + (size_t)grow * K + k1, &Bs[cur ^ 1][c * 512]);
            }
        }
        #pragma unroll
        for (int h = 0; h < 2; ++h) {
            short8 af[4], bf[4];
            #pragma unroll
            for (int mi = 0; mi < 4; ++mi) {
                const int row = wm * 64 + mi * 16 + lr;
                const int slot = (h * 4 + lg) ^ (row & 7);
                af[mi] = *(const short8*)(&As[cur][row * 64 + slot * 8]);
            }
            #pragma unroll
            for (int ni = 0; ni < 4; ++ni) {
                const int row = wn * 64 + ni * 16 + lr;
                const int slot = (h * 4 + lg) ^ (row & 7);
                bf[ni] = *(const short8*)(&Bs[cur][row * 64 + slot * 8]);
            }
            #pragma unroll
            for (int mi = 0; mi < 4; ++mi)
                #pragma unroll
                for (int ni = 0; ni < 4; ++ni)
                    acc[mi][ni] = __builtin_amdgcn_mfma_f32_16x16x32_bf16(af[mi], bf[ni], acc[mi][ni], 0, 0, 0);
        }
        __syncthreads();
        cur ^= 1;
    }

    const int seg = blockIdx.x >> 3;                 // 0=Q,1=K,2=V segment
    const float* bp = (seg == 0) ? b0 : (seg == 1) ? b1 : b2;
    const float osc = (seg == 0) ? qscale : 1.0f;
    #pragma unroll
    for (int ni = 0; ni < 4; ++ni) {
        const int n = n0 + wn * 64 + ni * 16 + lr;
        const float bv = bp[n & 1023];
        #pragma unroll
        for (int mi = 0; mi < 4; ++mi) {
            const int mb = m0 + wm * 64 + mi * 16 + lg * 4;
            #pragma unroll
            for (int i = 0; i < 4; ++i) {
                const float val = (acc[mi][ni][i] + bv) * osc;
                if (OUT_BF16) ((unsigned short*)out)[(size_t)(mb + i) * N + n] = f2bf(val);
                else          ((float*)out)[(size_t)(mb + i) * N + n] = val;
            }
        }
    }
}

// ---------------- MFMA causal flash attention: swapped QK^T, scalar m/l ----------------
// S^T = mfma(K,Q): lane (lr,lg) holds S[q=lr][kk=s4*16+lg*4+reg] -> softmax
// row-reduce = 15 in-reg ops + 2 shuffles; m,l are per-lane scalars.
// P packed to dwords in-register, staged via 8 KB swizzled LDS to PV A-frags.
// LDS total 40 KB -> 4 blocks/CU. 2-phase K/V pipeline, defer-max, setprio.
__global__ __launch_bounds__(256) void flash_attn(const unsigned short* __restrict__ QKV,
                                                  const unsigned short* __restrict__ Vt,
                                                  unsigned short* __restrict__ Mo) {
    __shared__ __attribute__((aligned(16))) unsigned short KtL[2][KBLK * 64];  // 16 KB
    __shared__ __attribute__((aligned(16))) unsigned short VsL[2][64 * KBLK];  // 16 KB
    __shared__ __attribute__((aligned(16))) unsigned int   Pq[4 * 16 * 32];    // 8 KB

    const int tid  = threadIdx.x;
    const int lane = tid & 63;
    const int w    = tid >> 6;
    const int F   = blockIdx.x;
    const int xcd = F & 7;
    const int r_  = F >> 3;
    const int qb  = 31 - (r_ & 31);
    const int bh  = xcd | ((r_ >> 5) << 3);
    const int b = bh >> 4, h = bh & 15;
    const int q0 = qb * QBLK;
    const int lg = lane >> 4;
    const int lr = lane & 15;

    const size_t tokbase = (size_t)b * SEQ;
    const size_t hoff = (size_t)h * D_HEAD;

    const int crow  = lane >> 3;
    const int uslot = (lane & 7) ^ crow;

    // Q fragments (pre-scaled by 0.125*log2e at projection)
    const short* Qp = (const short*)QKV + (tokbase + q0 + w * 16 + lr) * D_QKV + hoff + lg * 8;
    const short8 qf0 = *(const short8*)(Qp);
    const short8 qf1 = *(const short8*)(Qp + 32);

    const unsigned short* Kg = QKV + (tokbase) * D_QKV + 1024 + hoff + uslot * 8;  // + row*D_QKV
    const unsigned short* Vg = Vt + ((size_t)bh * 64) * SEQ + uslot * 8;           // + row*SEQ

    // swizzled K/V LDS fragment offsets (shorts)
    int koff[2][4];
    #pragma unroll
    for (int hh = 0; hh < 2; ++hh)
        #pragma unroll
        for (int s4 = 0; s4 < 4; ++s4)
            koff[hh][s4] = (s4 * 16 + lr) * 64 + (((hh * 4 + lg) ^ (lr & 7)) * 8);

    // P dword-LDS addressing: layout [w][16 q][32 dw], swizzle dw bits 3-4 ^= lr&3
    const int sxor = lr & 3;
    const int pw   = w * 512 + lr * 32 + lg * 2;            // + ((s4^sxor)<<3) + r2
    int prd[2];
    #pragma unroll
    for (int c2 = 0; c2 < 2; ++c2)
        prd[c2] = w * 512 + lr * 32 + (lg & 1) * 4 + ((((c2 << 1) + (lg >> 1)) ^ sxor) << 3);

    // bpermute byte-addresses for q-row lg*4+i (stats live on lane lr=q)
    int qaddr[4];
    #pragma unroll
    for (int i = 0; i < 4; ++i) qaddr[i] = (lg * 4 + i) * 4;

    float m = -INFINITY, l = 0.f;
    f32x4 acc[4] = {};

    const int ntiles = qb + 1;

    // prologue: stage tile 0 into buf 0
    #pragma unroll
    for (int i = 0; i < 2; ++i) {
        const int c = w * 2 + i;
        const int row = c * 8 + crow;
        gload16(Kg + (size_t)row * D_QKV, &KtL[0][c * 512]);
        gload16(Vg + (size_t)row * SEQ, &VsL[0][c * 512]);
    }
    __syncthreads();

    int cur = 0;
    for (int t = 0; t < ntiles; ++t) {
        if (t + 1 < ntiles) {
            const int k1 = (t + 1) * KBLK;
            #pragma unroll
            for (int i = 0; i < 2; ++i) {
                const int c = w * 2 + i;
                const int row = c * 8 + crow;
                gload16(Kg + (size_t)(k1 + row) * D_QKV, &KtL[cur ^ 1][c * 512]);
                gload16(Vg + (size_t)row * SEQ + k1, &VsL[cur ^ 1][c * 512]);
            }
        }
        const unsigned short* Kc = KtL[cur];
        const unsigned short* Vc = VsL[cur];

        // swapped QK^T: st[s4][reg] = S[q=lr][kk = s4*16 + lg*4 + reg]
        f32x4 st[4];
        __builtin_amdgcn_s_setprio(1);
        #pragma unroll
        for (int s4 = 0; s4 < 4; ++s4) {
            const short8 kf0 = *(const short8*)(Kc + koff[0][s4]);
            const short8 kf1 = *(const short8*)(Kc + koff[1][s4]);
            f32x4 z = {0.f, 0.f, 0.f, 0.f};
            z = __builtin_amdgcn_mfma_f32_16x16x32_bf16(kf0, qf0, z, 0, 0, 0);
            z = __builtin_amdgcn_mfma_f32_16x16x32_bf16(kf1, qf1, z, 0, 0, 0);
            st[s4] = z;
        }
        __builtin_amdgcn_s_setprio(0);

        // causal mask on the diagonal tile only
        if (t == qb) {
            const int qloc = w * 16 + lr;
            #pragma unroll
            for (int s4 = 0; s4 < 4; ++s4) {
                const int kb = s4 * 16 + lg * 4;
                #pragma unroll
                for (int r = 0; r < 4; ++r)
                    st[s4][r] = (kb + r <= qloc) ? st[s4][r] : -INFINITY;
            }
        }

        // row max over own 16 + 2-shuffle butterfly
        float pmax = st[0][0];
        #pragma unroll
        for (int s4 = 0; s4 < 4; ++s4)
            #pragma unroll
            for (int r = 0; r < 4; ++r) pmax = fmaxf(pmax, st[s4][r]);
        pmax = fmaxf(pmax, __shfl_xor(pmax, 16));
        pmax = fmaxf(pmax, __shfl_xor(pmax, 32));

        // defer-max: rescale only when some row grew by > 8 (exp2 domain)
        if (__any(pmax > m + 8.0f)) {
            const float mn = fmaxf(m, pmax);
            const float c  = __builtin_exp2f(m - mn);
            m = mn;
            l *= c;
            #pragma unroll
            for (int i = 0; i < 4; ++i) {
                const float cb = __uint_as_float(
                    (unsigned)__builtin_amdgcn_ds_bpermute(qaddr[i], (int)__float_as_uint(c)));
                #pragma unroll
                for (int ds = 0; ds < 4; ++ds) acc[ds][i] *= cb;
            }
        }

        // p = exp2(s - m); pack to bf16 dwords; write swizzled P; row-sum
        float rs = 0.f;
        #pragma unroll
        for (int s4 = 0; s4 < 4; ++s4) {
            float p0 = __builtin_exp2f(st[s4][0] - m);
            float p1 = __builtin_exp2f(st[s4][1] - m);
            float p2 = __builtin_exp2f(st[s4][2] - m);
            float p3 = __builtin_exp2f(st[s4][3] - m);
            rs += (p0 + p1) + (p2 + p3);
            const unsigned u0 = __float_as_uint(p0) + 0x8000u;
            const unsigned u1 = __float_as_uint(p1) + 0x8000u;
            const unsigned u2 = __float_as_uint(p2) + 0x8000u;
            const unsigned u3 = __float_as_uint(p3) + 0x8000u;
            const int pb = pw + (((s4 ^ sxor) << 3));
            Pq[pb]     = (u1 & 0xffff0000u) | (u0 >> 16);
            Pq[pb + 1] = (u3 & 0xffff0000u) | (u2 >> 16);
        }
        rs += __shfl_xor(rs, 16);
        rs += __shfl_xor(rs, 32);
        l += rs;

        // PV: A = P (rows=q), B = V^T (rows=d)
        __builtin_amdgcn_s_setprio(1);
        #pragma unroll
        for (int c2 = 0; c2 < 2; ++c2) {
            const short8 pf = *(const short8*)(Pq + prd[c2]);
            #pragma unroll
            for (int ds = 0; ds < 4; ++ds) {
                const short8 vf = *(const short8*)(Vc + koff[c2][ds]);
                acc[ds] = __builtin_amdgcn_mfma_f32_16x16x32_bf16(pf, vf, acc[ds], 0, 0, 0);
            }
        }
        __builtin_amdgcn_s_setprio(0);

        __syncthreads();     // drains next-tile loads; protects K/V buffers
        cur ^= 1;
    }

    // epilogue: redistribute 1/l to acc layout (q = lg*4+i), write merged
    const float linv = 1.0f / l;
    float lb[4];
    #pragma unroll
    for (int i = 0; i < 4; ++i)
        lb[i] = __uint_as_float(
            (unsigned)__builtin_amdgcn_ds_bpermute(qaddr[i], (int)__float_as_uint(linv)));
    const int gq = q0 + w * 16 + lg * 4;
    #pragma unroll
    for (int ds = 0; ds < 4; ++ds) {
        #pragma unroll
        for (int i = 0; i < 4; ++i) {
            const float o = acc[ds][i] * lb[i];
            Mo[(tokbase + gq + i) * D_MODEL + hoff + ds * 16 + lr] = f2bf(o);
        }
    }
}

extern "C" void kernel_launch(void* const* d_in, const int* in_sizes, int n_in,
                              void* d_out, int out_size, void* d_ws, size_t ws_size,
                              hipStream_t stream) {
    const float* X  = (const float*)d_in[0];
    const float* lg = (const float*)d_in[1];
    const float* lb = (const float*)d_in[2];
    const float* Wq = (const float*)d_in[3];
    const float* bq = (const float*)d_in[4];
    const float* Wk = (const float*)d_in[5];
    const float* bk = (const float*)d_in[6];
    const float* Wv = (const float*)d_in[7];
    const float* bv = (const float*)d_in[8];
    const float* Wo = (const float*)d_in[9];
    const float* bo = (const float*)d_in[10];
    float* out = (float*)d_out;

    char* ws = (char*)d_ws;
    const size_t MB = 1024 * 1024;
    unsigned short* Xn   = (unsigned short*)(ws + 0);          // 16 MB (dead after QKV gemm)
    unsigned short* Vtg  = (unsigned short*)(ws + 0);          // V^T reuses Xn slot
    unsigned short* Wqkv = (unsigned short*)(ws + 16 * MB);    // 6 MB fused [3072][1024]
    unsigned short* WoB  = (unsigned short*)(ws + 22 * MB);    // 2 MB
    unsigned short* QKVb = (unsigned short*)(ws + 24 * MB);    // 48 MB [8192][3072]
    unsigned short* Mb   = (unsigned short*)(ws + 72 * MB);    // 16 MB merged AV

    // 1. LayerNorm -> Xn (bf16)
    ln_kernel<<<TOKENS, 256, 0, stream>>>(X, lg, lb, Xn);

    // 2. fused weight convert
    cvt_all<<<4096, 256, 0, stream>>>(Wq, Wk, Wv, Wo, Wqkv, WoB);

    // 3. fused QKV projection (Q-segment scaled by 0.125*log2e)
    const float qscale = 0.125f * 1.44269504088896f;
    dim3 qkvgrid(D_QKV / 128, TOKENS / 128);
    gemm128<true><<<qkvgrid, 256, 0, stream>>>(Xn, Wqkv, bq, bk, bv, QKVb,
                                               TOKENS, D_QKV, D_MODEL, qscale);

    // 3b. V-part of QKV -> V^T
    dim3 tgrid(SEQ / 64, D_MODEL / 64, BATCH);
    transpose_v<<<tgrid, 256, 0, stream>>>(QKVb, Vtg);

    // 4. MFMA causal flash attention (1D XCD-grouped grid)
    flash_attn<<<(SEQ / QBLK) * BATCH * N_HEADS, 256, 0, stream>>>(QKVb, Vtg, Mb);

    // 5. output projection -> d_out (f32)
    dim3 ogrid(D_MODEL / 128, TOKENS / 128);
    gemm128<false><<<ogrid, 256, 0, stream>>>(Mb, WoB, bo, bo, bo, out,
                                              TOKENS, D_MODEL, D_MODEL, 1.0f);
}

// Round 9
// 303.675 us; speedup vs baseline: 32.9048x; 1.0236x over previous
//
#include <hip/hip_runtime.h>

#define D_MODEL 1024
#define N_HEADS 16
#define D_HEAD 64
#define BATCH 4
#define SEQ 2048
#define TOKENS (BATCH * SEQ)   // 8192
#define D_QKV 3072             // fused Q|K|V weight rows
#define QKSTR 2048             // Q|K activation buffer stride

#define QBLK 64
#define KBLK 64

typedef __attribute__((ext_vector_type(8))) short short8;
typedef __attribute__((ext_vector_type(4))) short short4v;
typedef __attribute__((ext_vector_type(4))) unsigned short us4;
typedef __attribute__((ext_vector_type(4))) float f32x4;

__device__ __forceinline__ unsigned short f2bf(float f) {
    unsigned u = __float_as_uint(f);
    u += 0x7fffu + ((u >> 16) & 1u);   // round-to-nearest-even
    return (unsigned short)(u >> 16);
}
__device__ __forceinline__ void gload16(const unsigned short* g, unsigned short* lds) {
    __builtin_amdgcn_global_load_lds((const __attribute__((address_space(1))) void*)g,
                                     (__attribute__((address_space(3))) void*)lds, 16, 0, 0);
}

// ---------------- LayerNorm: one block (256 thr) per token, f32 -> bf16 ----------------
__global__ void ln_kernel(const float* __restrict__ X, const float* __restrict__ gamma,
                          const float* __restrict__ beta, unsigned short* __restrict__ Xn) {
    const int t = blockIdx.x;
    const int tid = threadIdx.x;                      // 0..255
    const float4 v = ((const float4*)(X + (size_t)t * D_MODEL))[tid];
    float s  = v.x + v.y + v.z + v.w;
    float s2 = v.x * v.x + v.y * v.y + v.z * v.z + v.w * v.w;
    for (int off = 32; off > 0; off >>= 1) {
        s  += __shfl_xor(s,  off);
        s2 += __shfl_xor(s2, off);
    }
    __shared__ float sh[8];
    const int wv = tid >> 6;
    if ((tid & 63) == 0) { sh[wv] = s; sh[4 + wv] = s2; }
    __syncthreads();
    const float ts  = sh[0] + sh[1] + sh[2] + sh[3];
    const float ts2 = sh[4] + sh[5] + sh[6] + sh[7];
    const float mu  = ts * (1.0f / D_MODEL);
    const float var = ts2 * (1.0f / D_MODEL) - mu * mu;
    const float rs  = rsqrtf(var + 1e-5f);
    const float4 gm = ((const float4*)gamma)[tid];
    const float4 bt = ((const float4*)beta)[tid];
    ushort4 o;
    o.x = f2bf((v.x - mu) * rs * gm.x + bt.x);
    o.y = f2bf((v.y - mu) * rs * gm.y + bt.y);
    o.z = f2bf((v.z - mu) * rs * gm.z + bt.z);
    o.w = f2bf((v.w - mu) * rs * gm.w + bt.w);
    ((ushort4*)Xn)[(size_t)t * (D_MODEL / 4) + tid] = o;
}

// ---------------- fused weight convert: Wq|Wk|Wv -> Wqkv rows, Wo -> WoB ----------------
__global__ void cvt_all(const float* __restrict__ Wq, const float* __restrict__ Wk,
                        const float* __restrict__ Wv, const float* __restrict__ Wo,
                        unsigned short* __restrict__ Wqkv, unsigned short* __restrict__ WoB) {
    const int i = blockIdx.x * blockDim.x + threadIdx.x;
    const int mtx  = i >> 18;
    const int elem = i & 262143;
    const float* src;
    unsigned short* dst;
    if (mtx == 0)      { src = Wq; dst = Wqkv; }
    else if (mtx == 1) { src = Wk; dst = Wqkv + (1 << 20); }
    else if (mtx == 2) { src = Wv; dst = Wqkv + (2 << 20); }
    else               { src = Wo; dst = WoB; }
    const float4 v = ((const float4*)src)[elem];
    ushort4 o;
    o.x = f2bf(v.x); o.y = f2bf(v.y); o.z = f2bf(v.z); o.w = f2bf(v.w);
    ((ushort4*)dst)[elem] = o;
}

// ---------------- 128x128-tile NT GEMM, 2-phase double-buffered ----------------
// MODE 0: f32 out [(m)*N + n].
// MODE 2: fused QKV: seg0/1 (Q|K) -> bf16 out [(m)*QKSTR + n]; seg2 (V) ->
//         transposed bf16 into vtout[(b*1024 + n-2048)*SEQ + (m&2047)].
template <int MODE>
__global__ __launch_bounds__(256) void gemm128(const unsigned short* __restrict__ A,
                                               const unsigned short* __restrict__ B,
                                               const float* __restrict__ b0,
                                               const float* __restrict__ b1,
                                               const float* __restrict__ b2,
                                               void* __restrict__ out,
                                               unsigned short* __restrict__ vtout,
                                               int M, int N, int K, float qscale) {
    __shared__ __attribute__((aligned(16))) unsigned short As[2][128 * 64];   // 32 KB
    __shared__ __attribute__((aligned(16))) unsigned short Bs[2][128 * 64];   // 32 KB
    const int tid  = threadIdx.x;
    const int lane = tid & 63;
    const int w    = tid >> 6;
    const int wm = w >> 1, wn = w & 1;
    const int m0 = blockIdx.y * 128;
    const int n0 = blockIdx.x * 128;
    const int lr = lane & 15, lg = lane >> 4;

    const int crow  = lane >> 3;          // 0..7
    const int uslot = (lane & 7) ^ crow;  // inverse-swizzled source slot

    const unsigned short* Ab = A + (size_t)m0 * K + uslot * 8;
    const unsigned short* Bb = B + (size_t)n0 * K + uslot * 8;

    #pragma unroll
    for (int i = 0; i < 4; ++i) {
        const int c = w * 4 + i;
        const int grow = c * 8 + crow;
        gload16(Ab + (size_t)grow * K, &As[0][c * 512]);
        gload16(Bb + (size_t)grow * K, &Bs[0][c * 512]);
    }
    __syncthreads();

    f32x4 acc[4][4] = {};
    const int NT = K >> 6;
    int cur = 0;
    for (int kt = 0; kt < NT; ++kt) {
        if (kt + 1 < NT) {
            const int k1 = (kt + 1) << 6;
            #pragma unroll
            for (int i = 0; i < 4; ++i) {
                const int c = w * 4 + i;
                const int grow = c * 8 + crow;
                gload16(Ab + (size_t)grow * K + k1, &As[cur ^ 1][c * 512]);
                gload16(Bb + (size_t)grow * K + k1, &Bs[cur ^ 1][c * 512]);
            }
        }
        #pragma unroll
        for (int h = 0; h < 2; ++h) {
            short8 af[4], bf[4];
            #pragma unroll
            for (int mi = 0; mi < 4; ++mi) {
                const int row = wm * 64 + mi * 16 + lr;
                const int slot = (h * 4 + lg) ^ (row & 7);
                af[mi] = *(const short8*)(&As[cur][row * 64 + slot * 8]);
            }
            #pragma unroll
            for (int ni = 0; ni < 4; ++ni) {
                const int row = wn * 64 + ni * 16 + lr;
                const int slot = (h * 4 + lg) ^ (row & 7);
                bf[ni] = *(const short8*)(&Bs[cur][row * 64 + slot * 8]);
            }
            #pragma unroll
            for (int mi = 0; mi < 4; ++mi)
                #pragma unroll
                for (int ni = 0; ni < 4; ++ni)
                    acc[mi][ni] = __builtin_amdgcn_mfma_f32_16x16x32_bf16(af[mi], bf[ni], acc[mi][ni], 0, 0, 0);
        }
        __syncthreads();
        cur ^= 1;
    }

    const int seg = blockIdx.x >> 3;                 // 0=Q,1=K,2=V segment (MODE 2)
    const float* bp = (seg == 0) ? b0 : (seg == 1) ? b1 : b2;
    const float osc = (seg == 0) ? qscale : 1.0f;
    if (MODE == 2 && seg == 2) {
        // transposed V write: Vt[(b*1024 + n') * SEQ + s]
        #pragma unroll
        for (int ni = 0; ni < 4; ++ni) {
            const int np = n0 + wn * 64 + ni * 16 + lr - 2048;   // 0..1023
            const float bv = bp[np];
            #pragma unroll
            for (int mi = 0; mi < 4; ++mi) {
                const int mb = m0 + wm * 64 + mi * 16 + lg * 4;
                const int bb = mb >> 11;
                const int sm = mb & 2047;
                us4 o;
                #pragma unroll
                for (int i = 0; i < 4; ++i) o[i] = f2bf(acc[mi][ni][i] + bv);
                *(us4*)(vtout + (size_t)(bb * 1024 + np) * SEQ + sm) = o;
            }
        }
    } else {
        #pragma unroll
        for (int ni = 0; ni < 4; ++ni) {
            const int n = n0 + wn * 64 + ni * 16 + lr;
            const float bv = bp[n & 1023];
            #pragma unroll
            for (int mi = 0; mi < 4; ++mi) {
                const int mb = m0 + wm * 64 + mi * 16 + lg * 4;
                #pragma unroll
                for (int i = 0; i < 4; ++i) {
                    const float val = (acc[mi][ni][i] + bv) * osc;
                    if (MODE == 0) ((float*)out)[(size_t)(mb + i) * N + n] = val;
                    else           ((unsigned short*)out)[(size_t)(mb + i) * QKSTR + n] = f2bf(val);
                }
            }
        }
    }
}

// ---------------- MFMA causal flash attention: swapped QK^T + in-register PV ----------------
// S^T = mfma_x32(K,Q): lane (lr,lg) holds P[q=lr][k=s4*16+lg*4+r] -- which IS
// the mfma_16x16x16 B-fragment layout (k=(lane>>4)*4+r). PV = 4 chained
// mfma_f32_16x16x16bf16_1k per d-subtile with P packed in-register: no P-LDS,
// no bpermute (C/D col=lr=q matches softmax stats). LDS 32 KB -> 5 blocks/CU.
__global__ __launch_bounds__(256) void flash_attn(const unsigned short* __restrict__ QK,
                                                  const unsigned short* __restrict__ Vt,
                                                  unsigned short* __restrict__ Mo) {
    __shared__ __attribute__((aligned(16))) unsigned short KtL[2][KBLK * 64];  // 16 KB
    __shared__ __attribute__((aligned(16))) unsigned short VsL[2][64 * KBLK];  // 16 KB

    const int tid  = threadIdx.x;
    const int lane = tid & 63;
    const int w    = tid >> 6;
    const int F   = blockIdx.x;
    const int xcd = F & 7;
    const int r_  = F >> 3;
    const int qb  = 31 - (r_ & 31);
    const int bh  = xcd | ((r_ >> 5) << 3);
    const int b = bh >> 4, h = bh & 15;
    const int q0 = qb * QBLK;
    const int lg = lane >> 4;
    const int lr = lane & 15;

    const size_t tokbase = (size_t)b * SEQ;
    const size_t hoff = (size_t)h * D_HEAD;

    const int crow  = lane >> 3;
    const int uslot = (lane & 7) ^ crow;

    // Q fragments (pre-scaled by 0.125*log2e at projection); B-operand: col=lr=q
    const short* Qp = (const short*)QK + (tokbase + q0 + w * 16 + lr) * QKSTR + hoff + lg * 8;
    const short8 qf0 = *(const short8*)(Qp);
    const short8 qf1 = *(const short8*)(Qp + 32);

    // staging source pointers (advance per tile)
    const unsigned short* kld[2];
    const unsigned short* vld[2];
    kld[0] = QK + (tokbase + w * 16 + crow) * QKSTR + 1024 + hoff + uslot * 8;
    kld[1] = kld[0] + (size_t)8 * QKSTR;
    vld[0] = Vt + ((size_t)bh * 64 + w * 16 + crow) * SEQ + uslot * 8;
    vld[1] = vld[0] + (size_t)8 * SEQ;

    // K b128 fragment offsets (QK^T A-operand: row = k-token)
    int koff[2][4];
    #pragma unroll
    for (int hh = 0; hh < 2; ++hh)
        #pragma unroll
        for (int s4 = 0; s4 < 4; ++s4)
            koff[hh][s4] = (s4 * 16 + lr) * 64 + (((hh * 4 + lg) ^ (lr & 7)) * 8);
    // V b64 fragment offsets (PV x16 A-operand: row = d = ds*16+lr, k = s4*16+lg*4)
    int voff[4][4];
    #pragma unroll
    for (int ds = 0; ds < 4; ++ds)
        #pragma unroll
        for (int s4 = 0; s4 < 4; ++s4)
            voff[ds][s4] = (ds * 16 + lr) * 64 + (((s4 * 2 + (lg >> 1)) ^ (lr & 7)) << 3) + ((lg & 1) << 2);

    float m = -INFINITY, l = 0.f;
    f32x4 acc[4] = {};          // acc[ds][i] = O[q=lr][d = ds*16 + lg*4 + i]

    const int ntiles = qb + 1;

    // prologue: stage tile 0 into buf 0
    gload16(kld[0], &KtL[0][(w * 2) * 512]);
    gload16(kld[1], &KtL[0][(w * 2 + 1) * 512]);
    gload16(vld[0], &VsL[0][(w * 2) * 512]);
    gload16(vld[1], &VsL[0][(w * 2 + 1) * 512]);
    __syncthreads();

    int cur = 0;
    for (int t = 0; t < ntiles; ++t) {
        if (t + 1 < ntiles) {
            #pragma unroll
            for (int i = 0; i < 2; ++i) {
                kld[i] += (size_t)KBLK * QKSTR;
                vld[i] += KBLK;
                gload16(kld[i], &KtL[cur ^ 1][(w * 2 + i) * 512]);
                gload16(vld[i], &VsL[cur ^ 1][(w * 2 + i) * 512]);
            }
        }
        const unsigned short* Kc = KtL[cur];
        const unsigned short* Vc = VsL[cur];

        // swapped QK^T: st[s4][r] = S[q=lr][kk = s4*16 + lg*4 + r] (exp2 domain)
        f32x4 st[4];
        __builtin_amdgcn_s_setprio(1);
        #pragma unroll
        for (int s4 = 0; s4 < 4; ++s4) {
            const short8 kf0 = *(const short8*)(Kc + koff[0][s4]);
            const short8 kf1 = *(const short8*)(Kc + koff[1][s4]);
            f32x4 z = {0.f, 0.f, 0.f, 0.f};
            z = __builtin_amdgcn_mfma_f32_16x16x32_bf16(kf0, qf0, z, 0, 0, 0);
            z = __builtin_amdgcn_mfma_f32_16x16x32_bf16(kf1, qf1, z, 0, 0, 0);
            st[s4] = z;
        }
        __builtin_amdgcn_s_setprio(0);

        // causal mask on the diagonal tile only
        if (t == qb) {
            const int qloc = w * 16 + lr;
            #pragma unroll
            for (int s4 = 0; s4 < 4; ++s4) {
                const int kb = s4 * 16 + lg * 4;
                #pragma unroll
                for (int r = 0; r < 4; ++r)
                    st[s4][r] = (kb + r <= qloc) ? st[s4][r] : -INFINITY;
            }
        }

        // row max over own 16 + 2-shuffle butterfly (q-group = lanes lr+16*lg)
        float pmax = st[0][0];
        #pragma unroll
        for (int s4 = 0; s4 < 4; ++s4)
            #pragma unroll
            for (int r = 0; r < 4; ++r) pmax = fmaxf(pmax, st[s4][r]);
        pmax = fmaxf(pmax, __shfl_xor(pmax, 16));
        pmax = fmaxf(pmax, __shfl_xor(pmax, 32));

        // defer-max: rescale only when some row grew by > 8 (exp2 domain)
        if (__any(pmax > m + 8.0f)) {
            const float mn = fmaxf(m, pmax);
            const float c  = __builtin_exp2f(m - mn);
            m = mn;
            l *= c;
            #pragma unroll
            for (int ds = 0; ds < 4; ++ds)
                #pragma unroll
                for (int i = 0; i < 4; ++i) acc[ds][i] *= c;
        }

        // p = exp2(s - m); row-sum; pack; PV via 16x16x16 (B = in-register P)
        float rs = 0.f;
        #pragma unroll
        for (int s4 = 0; s4 < 4; ++s4) {
            #pragma unroll
            for (int r = 0; r < 4; ++r) {
                const float p = __builtin_exp2f(st[s4][r] - m);
                st[s4][r] = p;
                rs += p;
            }
        }
        rs += __shfl_xor(rs, 16);
        rs += __shfl_xor(rs, 32);
        l += rs;

        __builtin_amdgcn_s_setprio(1);
        #pragma unroll
        for (int s4 = 0; s4 < 4; ++s4) {
            short4v pf;
            #pragma unroll
            for (int r = 0; r < 4; ++r)
                pf[r] = (short)((__float_as_uint(st[s4][r]) + 0x8000u) >> 16);
            #pragma unroll
            for (int ds = 0; ds < 4; ++ds) {
                const short4v vf = *(const short4v*)(Vc + voff[ds][s4]);
                acc[ds] = __builtin_amdgcn_mfma_f32_16x16x16bf16_1k(vf, pf, acc[ds], 0, 0, 0);
            }
        }
        __builtin_amdgcn_s_setprio(0);

        __syncthreads();     // drains next-tile loads; protects K/V buffers
        cur ^= 1;
    }

    // epilogue: per-lane scalar 1/l (q = lr), vectorized 8B stores
    const float linv = 1.0f / l;
    const size_t obase = (tokbase + q0 + w * 16 + lr) * D_MODEL + hoff + lg * 4;
    #pragma unroll
    for (int ds = 0; ds < 4; ++ds) {
        us4 o;
        #pragma unroll
        for (int i = 0; i < 4; ++i) o[i] = f2bf(acc[ds][i] * linv);
        *(us4*)(Mo + obase + ds * 16) = o;
    }
}

extern "C" void kernel_launch(void* const* d_in, const int* in_sizes, int n_in,
                              void* d_out, int out_size, void* d_ws, size_t ws_size,
                              hipStream_t stream) {
    const float* X  = (const float*)d_in[0];
    const float* lg = (const float*)d_in[1];
    const float* lb = (const float*)d_in[2];
    const float* Wq = (const float*)d_in[3];
    const float* bq = (const float*)d_in[4];
    const float* Wk = (const float*)d_in[5];
    const float* bk = (const float*)d_in[6];
    const float* Wv = (const float*)d_in[7];
    const float* bv = (const float*)d_in[8];
    const float* Wo = (const float*)d_in[9];
    const float* bo = (const float*)d_in[10];
    float* out = (float*)d_out;

    char* ws = (char*)d_ws;
    const size_t MB = 1024 * 1024;
    unsigned short* Xn   = (unsigned short*)(ws + 0);          // 16 MB (LN out)
    unsigned short* Wqkv = (unsigned short*)(ws + 16 * MB);    // 6 MB fused [3072][1024]
    unsigned short* WoB  = (unsigned short*)(ws + 22 * MB);    // 2 MB
    unsigned short* QKb  = (unsigned short*)(ws + 24 * MB);    // 32 MB [8192][2048] Q|K
    unsigned short* Vtg  = (unsigned short*)(ws + 56 * MB);    // 16 MB V^T [b*1024+n'][s]
    unsigned short* Mb   = (unsigned short*)(ws + 72 * MB);    // 16 MB merged AV

    // 1. LayerNorm -> Xn (bf16)
    ln_kernel<<<TOKENS, 256, 0, stream>>>(X, lg, lb, Xn);

    // 2. fused weight convert
    cvt_all<<<4096, 256, 0, stream>>>(Wq, Wk, Wv, Wo, Wqkv, WoB);

    // 3. fused QKV projection; Q scaled by 0.125*log2e; V written transposed
    const float qscale = 0.125f * 1.44269504088896f;
    dim3 qkvgrid(D_QKV / 128, TOKENS / 128);
    gemm128<2><<<qkvgrid, 256, 0, stream>>>(Xn, Wqkv, bq, bk, bv, QKb, Vtg,
                                            TOKENS, D_QKV, D_MODEL, qscale);

    // 4. MFMA causal flash attention (1D XCD-grouped grid)
    flash_attn<<<(SEQ / QBLK) * BATCH * N_HEADS, 256, 0, stream>>>(QKb, Vtg, Mb);

    // 5. output projection -> d_out (f32)
    dim3 ogrid(D_MODEL / 128, TOKENS / 128);
    gemm128<0><<<ogrid, 256, 0, stream>>>(Mb, WoB, bo, bo, bo, out, nullptr,
                                          TOKENS, D_MODEL, D_MODEL, 1.0f);
}